// Round 8
// baseline (468.179 us; speedup 1.0000x reference)
//
#include <hip/hip_runtime.h>
#include <math.h>

#define NNODES 50000

typedef __attribute__((ext_vector_type(8))) short short8;   // 8 bf16 (4 VGPRs)
typedef __attribute__((ext_vector_type(4))) float f32x4;    // MFMA accumulator

__device__ __forceinline__ unsigned short f2bf(float f) {
    unsigned u = __float_as_uint(f);
    u += 0x7fffu + ((u >> 16) & 1);   // RTN-even
    return (unsigned short)(u >> 16);
}
__device__ __forceinline__ float bf2f(unsigned short h) {
    return __uint_as_float(((unsigned)h) << 16);
}
__device__ __forceinline__ float bflo(unsigned u) { return __uint_as_float(u << 16); }
__device__ __forceinline__ float bfhi(unsigned u) { return __uint_as_float(u & 0xffff0000u); }

// ---------------- CSR build ----------------
// deg[] is zeroed via hipMemsetAsync; self-loop (+1) folded into the scan reads.
__global__ __launch_bounds__(256) void deg_count_kernel(const int* __restrict__ ei,
                                                        int* __restrict__ deg, int E) {
    int i = blockIdx.x * 256 + threadIdx.x;
    if (i < E) atomicAdd(&deg[ei[E + i]], 1);
}

__global__ __launch_bounds__(256) void scan_partial_kernel(const int* __restrict__ deg,
                                                           int* __restrict__ bsum, int N) {
    __shared__ int ls[256];
    int t = threadIdx.x;
    int i = blockIdx.x * 256 + t;
    ls[t] = (i < N) ? deg[i] + 1 : 0;   // +1 self-loop
    __syncthreads();
    #pragma unroll
    for (int off = 128; off; off >>= 1) {
        if (t < off) ls[t] += ls[t + off];
        __syncthreads();
    }
    if (t == 0) bsum[blockIdx.x] = ls[0];
}

__global__ __launch_bounds__(256) void scan_blocks_kernel(const int* __restrict__ bsum,
                                                          int* __restrict__ boff,
                                                          int* __restrict__ rowptrN, int nblk) {
    __shared__ int ls[256];
    int t = threadIdx.x;
    int v = (t < nblk) ? bsum[t] : 0;
    ls[t] = v;
    __syncthreads();
    for (int off = 1; off < 256; off <<= 1) {
        int u = (t >= off) ? ls[t - off] : 0;
        __syncthreads();
        ls[t] += u;
        __syncthreads();
    }
    if (t < nblk) boff[t] = ls[t] - v;
    if (t == 255) *rowptrN = ls[255];
}

__global__ __launch_bounds__(256) void scan_final_kernel(const int* __restrict__ deg,
                                                         const int* __restrict__ boff,
                                                         int* __restrict__ rowptr,
                                                         int* __restrict__ fill, int N) {
    __shared__ int ls[256];
    int t = threadIdx.x;
    int i = blockIdx.x * 256 + t;
    int v = (i < N) ? deg[i] + 1 : 0;   // +1 self-loop
    ls[t] = v;
    __syncthreads();
    for (int off = 1; off < 256; off <<= 1) {
        int u = (t >= off) ? ls[t - off] : 0;
        __syncthreads();
        ls[t] += u;
        __syncthreads();
    }
    if (i < N) {
        int e = boff[blockIdx.x] + ls[t] - v;
        rowptr[i] = e;
        fill[i] = e;
    }
}

__global__ __launch_bounds__(256) void scatter_kernel(const int* __restrict__ ei,
                                                      int* __restrict__ fill,
                                                      int* __restrict__ col, int E, int N) {
    int i = blockIdx.x * 256 + threadIdx.x;
    int total = E + N;
    if (i >= total) return;
    int s, d;
    if (i < E) { s = ei[i]; d = ei[E + i]; }
    else       { s = i - E; d = s; }
    int pos = atomicAdd(&fill[d], 1);
    col[pos] = s;
}

// ---------------- weight prep (merged): transpose + split fp32 -> bf16 hi/lo, [n][k] ----------------
__global__ __launch_bounds__(256) void wprep_kernel(const float* __restrict__ W2,
                                                    const float* __restrict__ W3,
                                                    unsigned short* __restrict__ W2Th,
                                                    unsigned short* __restrict__ W2Tl,
                                                    unsigned short* __restrict__ W3Th,
                                                    unsigned short* __restrict__ W3Tl) {
    int b = blockIdx.x;
    if (b < 256) {            // W2: 256x256
        int k = b, n = threadIdx.x;
        float w = W2[k * 256 + n];
        unsigned short h = f2bf(w);
        unsigned short l = f2bf(w - bf2f(h));
        W2Th[n * 256 + k] = h;
        W2Tl[n * 256 + k] = l;
    } else {                  // W3: 256x64 -> [64][256]
        int n = b - 256, k = threadIdx.x;
        float w = W3[k * 64 + n];
        unsigned short h = f2bf(w);
        unsigned short l = f2bf(w - bf2f(h));
        W3Th[n * 256 + k] = h;
        W3Tl[n * 256 + k] = l;
    }
}

#define LDK 40

// ---------------- layer-2 GEMM: split-bf16 MFMA, pre-split A, fused es/ed epilogue ----------------
__global__ __launch_bounds__(256) void gemm2_mfma_kernel(const unsigned short* __restrict__ Ahb,
                                                         const unsigned short* __restrict__ Alb,
                                                         const unsigned short* __restrict__ WTh,
                                                         const unsigned short* __restrict__ WTl,
                                                         unsigned short* __restrict__ Cb,
                                                         const float* __restrict__ as_,
                                                         const float* __restrict__ ad_,
                                                         float* __restrict__ es,
                                                         float* __restrict__ ed,
                                                         int M) {
    __shared__ __align__(16) unsigned short Ah[128][LDK], Al[128][LDK];
    __shared__ __align__(16) unsigned short Bh[128][LDK], Bl[128][LDK];
    int tid  = threadIdx.x;
    int lane = tid & 63, wave = tid >> 6;
    int wm = wave >> 1, wn = wave & 1;
    int bm = blockIdx.x * 128;
    int bn = blockIdx.y * 128;
    int c = lane & 15, q = lane >> 4;

    f32x4 acc[4][4] = {};

    for (int k0 = 0; k0 < 256; k0 += 32) {
        #pragma unroll
        for (int p = 0; p < 2; ++p) {
            int idx = p * 256 + tid;
            int r   = idx >> 2;
            int kc  = (idx & 3) * 8;
            int grow = bm + r;
            size_t go = (size_t)grow * 256 + k0 + kc;
            uint4 vh = make_uint4(0u,0u,0u,0u), vl = make_uint4(0u,0u,0u,0u);
            if (grow < M) {
                vh = *reinterpret_cast<const uint4*>(Ahb + go);
                vl = *reinterpret_cast<const uint4*>(Alb + go);
            }
            *reinterpret_cast<uint4*>(&Ah[r][kc]) = vh;
            *reinterpret_cast<uint4*>(&Al[r][kc]) = vl;
        }
        #pragma unroll
        for (int p = 0; p < 2; ++p) {
            int idx = p * 256 + tid;
            int n   = idx >> 2;
            int kc  = (idx & 3) * 8;
            const size_t go = (size_t)(bn + n) * 256 + k0 + kc;
            *reinterpret_cast<uint4*>(&Bh[n][kc]) = *reinterpret_cast<const uint4*>(WTh + go);
            *reinterpret_cast<uint4*>(&Bl[n][kc]) = *reinterpret_cast<const uint4*>(WTl + go);
        }
        __syncthreads();

        short8 bh[4], bl[4];
        #pragma unroll
        for (int nt = 0; nt < 4; ++nt) {
            bh[nt] = *reinterpret_cast<const short8*>(&Bh[wn * 64 + nt * 16 + c][q * 8]);
            bl[nt] = *reinterpret_cast<const short8*>(&Bl[wn * 64 + nt * 16 + c][q * 8]);
        }
        #pragma unroll
        for (int mt = 0; mt < 4; ++mt) {
            short8 ah = *reinterpret_cast<const short8*>(&Ah[wm * 64 + mt * 16 + c][q * 8]);
            short8 al = *reinterpret_cast<const short8*>(&Al[wm * 64 + mt * 16 + c][q * 8]);
            #pragma unroll
            for (int nt = 0; nt < 4; ++nt) {
                acc[mt][nt] = __builtin_amdgcn_mfma_f32_16x16x32_bf16(ah, bh[nt], acc[mt][nt], 0, 0, 0);
                acc[mt][nt] = __builtin_amdgcn_mfma_f32_16x16x32_bf16(ah, bl[nt], acc[mt][nt], 0, 0, 0);
                acc[mt][nt] = __builtin_amdgcn_mfma_f32_16x16x32_bf16(al, bh[nt], acc[mt][nt], 0, 0, 0);
            }
        }
        __syncthreads();
    }

    #pragma unroll
    for (int mt = 0; mt < 4; ++mt) {
        #pragma unroll
        for (int r = 0; r < 4; ++r) {
            int gr = bm + wm * 64 + mt * 16 + q * 4 + r;
            if (gr < M) {
                #pragma unroll
                for (int nt = 0; nt < 4; ++nt) {
                    Cb[(size_t)gr * 256 + bn + wn * 64 + nt * 16 + c] = f2bf(acc[mt][nt][r]);
                }
            }
        }
    }
    int head = blockIdx.y * 2 + wn;
    float asv[4], adv[4];
    #pragma unroll
    for (int nt = 0; nt < 4; ++nt) {
        asv[nt] = as_[head * 64 + nt * 16 + c];
        adv[nt] = ad_[head * 64 + nt * 16 + c];
    }
    #pragma unroll
    for (int mt = 0; mt < 4; ++mt) {
        #pragma unroll
        for (int r = 0; r < 4; ++r) {
            float s = 0.f, d = 0.f;
            #pragma unroll
            for (int nt = 0; nt < 4; ++nt) {
                s += acc[mt][nt][r] * asv[nt];
                d += acc[mt][nt][r] * adv[nt];
            }
            #pragma unroll
            for (int off = 1; off < 16; off <<= 1) {
                s += __shfl_xor(s, off, 64);
                d += __shfl_xor(d, off, 64);
            }
            int gr = bm + wm * 64 + mt * 16 + q * 4 + r;
            if (c == 0 && gr < M) {
                es[(size_t)gr * 4 + head] = s;
                ed[(size_t)gr * 4 + head] = d;
            }
        }
    }
}

// ---------------- layer-3 GEMM: bf16-A MFMA, W3 split hi/lo ----------------
__global__ __launch_bounds__(256) void gemm3_mfma_kernel(const unsigned short* __restrict__ Ab,
                                                         const unsigned short* __restrict__ WTh,
                                                         const unsigned short* __restrict__ WTl,
                                                         unsigned short* __restrict__ Cb,
                                                         const float* __restrict__ as_,
                                                         const float* __restrict__ ad_,
                                                         float* __restrict__ es,
                                                         float* __restrict__ ed,
                                                         int M) {
    __shared__ __align__(16) unsigned short Ah[128][LDK];
    __shared__ __align__(16) unsigned short Bh[64][LDK], Bl[64][LDK];
    int tid = threadIdx.x, lane = tid & 63, wave = tid >> 6;
    int bm = blockIdx.x * 128;
    int c = lane & 15, q = lane >> 4;
    f32x4 acc[2][4] = {};

    for (int k0 = 0; k0 < 256; k0 += 32) {
        #pragma unroll
        for (int p = 0; p < 2; ++p) {
            int idx = p * 256 + tid;
            int r   = idx >> 2;
            int kf  = (idx & 3) * 8;
            int grow = bm + r;
            uint4 v = (grow < M)
                ? *reinterpret_cast<const uint4*>(Ab + (size_t)grow * 256 + k0 + kf)
                : make_uint4(0u, 0u, 0u, 0u);
            *reinterpret_cast<uint4*>(&Ah[r][kf]) = v;
        }
        {
            int n  = tid >> 2;
            int kc = (tid & 3) * 8;
            size_t go = (size_t)n * 256 + k0 + kc;
            *reinterpret_cast<uint4*>(&Bh[n][kc]) = *reinterpret_cast<const uint4*>(WTh + go);
            *reinterpret_cast<uint4*>(&Bl[n][kc]) = *reinterpret_cast<const uint4*>(WTl + go);
        }
        __syncthreads();

        short8 bh[4], bl[4];
        #pragma unroll
        for (int nt = 0; nt < 4; ++nt) {
            bh[nt] = *reinterpret_cast<const short8*>(&Bh[nt * 16 + c][q * 8]);
            bl[nt] = *reinterpret_cast<const short8*>(&Bl[nt * 16 + c][q * 8]);
        }
        #pragma unroll
        for (int mt = 0; mt < 2; ++mt) {
            short8 a = *reinterpret_cast<const short8*>(&Ah[wave * 32 + mt * 16 + c][q * 8]);
            #pragma unroll
            for (int nt = 0; nt < 4; ++nt) {
                acc[mt][nt] = __builtin_amdgcn_mfma_f32_16x16x32_bf16(a, bh[nt], acc[mt][nt], 0, 0, 0);
                acc[mt][nt] = __builtin_amdgcn_mfma_f32_16x16x32_bf16(a, bl[nt], acc[mt][nt], 0, 0, 0);
            }
        }
        __syncthreads();
    }

    float asv[4], adv[4];
    #pragma unroll
    for (int nt = 0; nt < 4; ++nt) { asv[nt] = as_[nt * 16 + c]; adv[nt] = ad_[nt * 16 + c]; }
    #pragma unroll
    for (int mt = 0; mt < 2; ++mt) {
        #pragma unroll
        for (int r = 0; r < 4; ++r) {
            int gr = bm + wave * 32 + mt * 16 + q * 4 + r;
            bool ok = gr < M;
            if (ok) {
                #pragma unroll
                for (int nt = 0; nt < 4; ++nt)
                    Cb[(size_t)gr * 64 + nt * 16 + c] = f2bf(acc[mt][nt][r]);
            }
            float s = 0.f, d = 0.f;
            #pragma unroll
            for (int nt = 0; nt < 4; ++nt) {
                s += acc[mt][nt][r] * asv[nt];
                d += acc[mt][nt][r] * adv[nt];
            }
            #pragma unroll
            for (int off = 1; off < 16; off <<= 1) {
                s += __shfl_xor(s, off, 64);
                d += __shfl_xor(d, off, 64);
            }
            if (c == 0 && ok) { es[gr] = s; ed[gr] = d; }
        }
    }
}

// ---------------- layer-1 fp32 GEMM (K=16) with fused es/ed epilogue ----------------
template <int H>
__global__ __launch_bounds__(256) void gemm_attn_kernel(const float* __restrict__ A,
                                                        const float* __restrict__ B,
                                                        unsigned short* __restrict__ Cb,
                                                        const float* __restrict__ as_,
                                                        const float* __restrict__ ad_,
                                                        float* __restrict__ es,
                                                        float* __restrict__ ed,
                                                        int M, int K, int Ncol) {
    __shared__ __align__(16) float As[16][64];
    __shared__ __align__(16) float Bs[16][64];
    int tid = threadIdx.x;
    int bm = blockIdx.x * 64;
    int bn = blockIdx.y * 64;
    int tm = (tid >> 4) * 4;
    int tn = (tid & 15) * 4;
    float acc[4][4] = {};
    int ar  = tid >> 2;
    int akk = (tid & 3) * 4;
    int brr = tid >> 4;
    int bcc = (tid & 15) * 4;
    for (int k0 = 0; k0 < K; k0 += 16) {
        int grow = bm + ar;
        float4 av;
        if (grow < M) av = *reinterpret_cast<const float4*>(A + (size_t)grow * K + k0 + akk);
        else          av = make_float4(0.f, 0.f, 0.f, 0.f);
        As[akk + 0][ar] = av.x;
        As[akk + 1][ar] = av.y;
        As[akk + 2][ar] = av.z;
        As[akk + 3][ar] = av.w;
        float4 bv = *reinterpret_cast<const float4*>(B + (size_t)(k0 + brr) * Ncol + bn + bcc);
        *reinterpret_cast<float4*>(&Bs[brr][bcc]) = bv;
        __syncthreads();
        #pragma unroll
        for (int kk = 0; kk < 16; ++kk) {
            float4 a4 = *reinterpret_cast<const float4*>(&As[kk][tm]);
            float4 b4 = *reinterpret_cast<const float4*>(&Bs[kk][tn]);
            float a[4] = {a4.x, a4.y, a4.z, a4.w};
            float b[4] = {b4.x, b4.y, b4.z, b4.w};
            #pragma unroll
            for (int i = 0; i < 4; ++i)
                #pragma unroll
                for (int j = 0; j < 4; ++j) acc[i][j] += a[i] * b[j];
        }
        __syncthreads();
    }
    #pragma unroll
    for (int i = 0; i < 4; ++i) {
        int gr = bm + tm + i;
        if (gr < M) {
            ushort4 r;
            r.x = f2bf(acc[i][0]); r.y = f2bf(acc[i][1]);
            r.z = f2bf(acc[i][2]); r.w = f2bf(acc[i][3]);
            *reinterpret_cast<ushort4*>(Cb + (size_t)gr * Ncol + bn + tn) = r;
        }
    }
    int hy = blockIdx.y;
    float4 asv = *reinterpret_cast<const float4*>(as_ + (size_t)hy * 64 + tn);
    float4 adv = *reinterpret_cast<const float4*>(ad_ + (size_t)hy * 64 + tn);
    float sv[4], dv[4];
    #pragma unroll
    for (int i = 0; i < 4; ++i) {
        sv[i] = acc[i][0] * asv.x + acc[i][1] * asv.y + acc[i][2] * asv.z + acc[i][3] * asv.w;
        dv[i] = acc[i][0] * adv.x + acc[i][1] * adv.y + acc[i][2] * adv.z + acc[i][3] * adv.w;
    }
    #pragma unroll
    for (int off = 1; off < 16; off <<= 1) {
        #pragma unroll
        for (int i = 0; i < 4; ++i) {
            sv[i] += __shfl_xor(sv[i], off, 64);
            dv[i] += __shfl_xor(dv[i], off, 64);
        }
    }
    if ((tid & 15) == 0) {
        #pragma unroll
        for (int i = 0; i < 4; ++i) {
            int gr = bm + tm + i;
            if (gr < M) {
                es[(size_t)gr * H + hy] = sv[i];
                ed[(size_t)gr * H + hy] = dv[i];
            }
        }
    }
}

__device__ __forceinline__ float lrelu02(float x) { return x > 0.f ? x : 0.2f * x; }
__device__ __forceinline__ float eluf(float x)    { return x > 0.f ? x : expm1f(x); }

// ---------------- fused per-dst aggregation, H=4, bf16 gather, single-pass softmax ----------------
// Full-wave gather: 64 lanes x 4 dims (uint2 = 8 B/lane), 1 edge per wave-iter (R6-proven form).
// OUTMODE: 0 = fp32, 1 = bf16 (gemm3 A), 2 = pre-split hi/lo bf16 (gemm2 A).
template <int ACT, int OUTMODE>
__global__ __launch_bounds__(256) void agg4_kernel(const unsigned short* __restrict__ hb,
                                                   const float* __restrict__ es,
                                                   const float* __restrict__ ed,
                                                   const int* __restrict__ rowptr,
                                                   const int* __restrict__ col,
                                                   const float* __restrict__ bias,
                                                   void* __restrict__ outp,
                                                   void* __restrict__ outp2, int N) {
    __shared__ int   slds[4][64];
    __shared__ float plds[4][4][68];   // +4 pad: heads land in different banks
    int sub  = threadIdx.x >> 6;
    int lane = threadIdx.x & 63;
    int node = blockIdx.x * 4 + sub;
    if (node >= N) return;
    int s = rowptr[node], t = rowptr[node + 1];

    float edv[4];
    #pragma unroll
    for (int h = 0; h < 4; ++h) edv[h] = ed[(size_t)node * 4 + h];

    float den[4] = {0.f, 0.f, 0.f, 0.f};
    int hh = lane >> 4;  // this lane's head (4 dims per lane)
    float4 acc = make_float4(0.f, 0.f, 0.f, 0.f);
    for (int base = s; base < t; base += 64) {
        int j = base + lane;
        int m = t - base; if (m > 64) m = 64;
        int sc = 0;
        float p[4] = {0.f, 0.f, 0.f, 0.f};
        if (j < t) {
            sc = col[j];
            float4 e4 = *reinterpret_cast<const float4*>(es + (size_t)sc * 4);
            p[0] = __expf(lrelu02(e4.x + edv[0]));
            p[1] = __expf(lrelu02(e4.y + edv[1]));
            p[2] = __expf(lrelu02(e4.z + edv[2]));
            p[3] = __expf(lrelu02(e4.w + edv[3]));
        }
        slds[sub][lane] = sc;
        #pragma unroll
        for (int h = 0; h < 4; ++h) {
            den[h] += p[h];
            plds[sub][h][lane] = p[h];
        }
        #pragma unroll 4
        for (int jj = 0; jj < m; ++jj) {
            int scj = slds[sub][jj];
            float a = plds[sub][hh][jj];
            uint2 u = *reinterpret_cast<const uint2*>(hb + (size_t)scj * 256 + lane * 4);
            acc.x += bflo(u.x) * a;
            acc.y += bfhi(u.x) * a;
            acc.z += bflo(u.y) * a;
            acc.w += bfhi(u.y) * a;
        }
    }
    #pragma unroll
    for (int off = 32; off; off >>= 1)
        #pragma unroll
        for (int h = 0; h < 4; ++h) den[h] += __shfl_xor(den[h], off, 64);
    float inv = 1.f / den[hh];
    float4 bv = *reinterpret_cast<const float4*>(bias + lane * 4);
    float r0 = acc.x * inv + bv.x;
    float r1 = acc.y * inv + bv.y;
    float r2 = acc.z * inv + bv.z;
    float r3 = acc.w * inv + bv.w;
    if (ACT) { r0 = eluf(r0); r1 = eluf(r1); r2 = eluf(r2); r3 = eluf(r3); }
    if constexpr (OUTMODE == 0) {
        *reinterpret_cast<float4*>((float*)outp + (size_t)node * 256 + lane * 4) =
            make_float4(r0, r1, r2, r3);
    } else if constexpr (OUTMODE == 1) {
        ushort4 o;
        o.x = f2bf(r0); o.y = f2bf(r1); o.z = f2bf(r2); o.w = f2bf(r3);
        *reinterpret_cast<ushort4*>((unsigned short*)outp + (size_t)node * 256 + lane * 4) = o;
    } else {
        ushort4 oh, ol;
        oh.x = f2bf(r0); ol.x = f2bf(r0 - bf2f(oh.x));
        oh.y = f2bf(r1); ol.y = f2bf(r1 - bf2f(oh.y));
        oh.z = f2bf(r2); ol.z = f2bf(r2 - bf2f(oh.z));
        oh.w = f2bf(r3); ol.w = f2bf(r3 - bf2f(oh.w));
        size_t o = (size_t)node * 256 + lane * 4;
        *reinterpret_cast<ushort4*>((unsigned short*)outp  + o) = oh;
        *reinterpret_cast<ushort4*>((unsigned short*)outp2 + o) = ol;
    }
}

// ---------------- fused per-dst aggregation, H=1, bf16 gather, half-wave uint loads ----------------
// 32 lanes x 2 dims (uint = 4 B/lane), 2 edges per wave-iter; combine halves via shfl_xor(32).
__global__ __launch_bounds__(256) void agg1_kernel(const unsigned short* __restrict__ hb,
                                                   const float* __restrict__ es,
                                                   const float* __restrict__ ed,
                                                   const int* __restrict__ rowptr,
                                                   const int* __restrict__ col,
                                                   const float* __restrict__ bias,
                                                   float* __restrict__ out, int N) {
    __shared__ int   slds[4][64];
    __shared__ float plds[4][64];
    int sub  = threadIdx.x >> 6;
    int lane = threadIdx.x & 63;
    int node = blockIdx.x * 4 + sub;
    if (node >= N) return;
    int s = rowptr[node], t = rowptr[node + 1];
    float edv = ed[node];

    int half = lane >> 5, sl = lane & 31;
    float den = 0.f, acc0 = 0.f, acc1 = 0.f;   // dims sl*2, sl*2+1
    for (int base = s; base < t; base += 64) {
        int j = base + lane;
        int m = t - base; if (m > 64) m = 64;
        int sc = 0;
        float p0 = 0.f;
        if (j < t) {
            sc = col[j];
            p0 = __expf(lrelu02(es[sc] + edv));
        }
        slds[sub][lane] = sc;
        plds[sub][lane] = p0;
        den += p0;
        int nit = (m + 1) >> 1;
        #pragma unroll 4
        for (int it = 0; it < nit; ++it) {
            int idx = 2 * it + half;          // phantom odd edge has p=0 (safe)
            int scj = slds[sub][idx];
            float a = plds[sub][idx];
            unsigned u = *reinterpret_cast<const unsigned*>(hb + (size_t)scj * 64 + sl * 2);
            acc0 += bflo(u) * a;
            acc1 += bfhi(u) * a;
        }
    }
    acc0 += __shfl_xor(acc0, 32, 64);
    acc1 += __shfl_xor(acc1, 32, 64);
    #pragma unroll
    for (int off = 32; off; off >>= 1) den += __shfl_xor(den, off, 64);
    if (half == 0) {
        float inv = 1.f / den;
        float2 b = *reinterpret_cast<const float2*>(bias + sl * 2);
        *reinterpret_cast<float2*>(out + (size_t)node * 64 + sl * 2) =
            make_float2(acc0 * inv + b.x, acc1 * inv + b.y);
    }
}

// ---------------- graph mean ----------------
__global__ __launch_bounds__(256) void gmean_partial(const float* __restrict__ ne,
                                                     float* __restrict__ part, int N) {
    int d = threadIdx.x & 63, sub = threadIdx.x >> 6;
    int start = blockIdx.x * 4 + sub;
    float s = 0.f;
    for (int n = start; n < N; n += gridDim.x * 4) s += ne[(size_t)n * 64 + d];
    __shared__ float ls[256];
    ls[threadIdx.x] = s;
    __syncthreads();
    if (threadIdx.x < 64) {
        float v = ls[threadIdx.x] + ls[threadIdx.x + 64] + ls[threadIdx.x + 128] + ls[threadIdx.x + 192];
        part[blockIdx.x * 64 + d] = v;
    }
}

__global__ __launch_bounds__(64) void gmean_final(const float* __restrict__ part,
                                                  float* __restrict__ gout, int nblk, float invN) {
    int d = threadIdx.x;
    float s = 0.f;
    for (int b = 0; b < nblk; ++b) s += part[b * 64 + d];
    gout[d] = s * invN;
}

extern "C" void kernel_launch(void* const* d_in, const int* in_sizes, int n_in,
                              void* d_out, int out_size, void* d_ws, size_t ws_size,
                              hipStream_t stream) {
    const float* x   = (const float*)d_in[0];
    const int*   ei  = (const int*)d_in[1];
    const float* W1  = (const float*)d_in[2];
    const float* a1s = (const float*)d_in[3];
    const float* a1d = (const float*)d_in[4];
    const float* b1  = (const float*)d_in[5];
    const float* W2  = (const float*)d_in[6];
    const float* a2s = (const float*)d_in[7];
    const float* a2d = (const float*)d_in[8];
    const float* b2  = (const float*)d_in[9];
    const float* W3  = (const float*)d_in[10];
    const float* a3s = (const float*)d_in[11];
    const float* a3d = (const float*)d_in[12];
    const float* b3  = (const float*)d_in[13];
    float* out = (float*)d_out;

    const int N = NNODES;
    const int E = in_sizes[1] / 2;  // 800000
    const int NB = (N + 255) / 256;

    // workspace carve (16B alignment maintained)
    char* w = (char*)d_ws;
    unsigned short* Hb   = (unsigned short*)w; w += (size_t)N * 256 * 2;  // h1/h2 bf16 (agg4 gather)
    unsigned short* B0b  = (unsigned short*)w; w += (size_t)N * 256 * 2;  // agg2 out bf16 (gemm3 A)
    unsigned short* H3b  = (unsigned short*)w; w += (size_t)N * 64 * 2;   // h3 bf16 (agg1 gather)
    unsigned short* A1h  = (unsigned short*)w; w += (size_t)N * 256 * 2;  // agg1(layer1) out hi (gemm2 A)
    unsigned short* A1l  = (unsigned short*)w; w += (size_t)N * 256 * 2;  // agg1(layer1) out lo
    float* es = (float*)w; w += (size_t)N * 4 * 4;
    float* ed = (float*)w; w += (size_t)N * 4 * 4;
    unsigned short* W2Th = (unsigned short*)w; w += 256 * 256 * 2;
    unsigned short* W2Tl = (unsigned short*)w; w += 256 * 256 * 2;
    unsigned short* W3Th = (unsigned short*)w; w += 64 * 256 * 2;
    unsigned short* W3Tl = (unsigned short*)w; w += 64 * 256 * 2;
    int* deg    = (int*)w; w += (size_t)N * 4;
    int* rowptr = (int*)w; w += (size_t)(N + 2) * 4;
    int* fill   = (int*)w; w += (size_t)N * 4;
    int* col    = (int*)w; w += (size_t)(E + N) * 4;
    int* bsum   = (int*)w; w += 256 * 4;
    int* boff   = (int*)w; w += 256 * 4;
    float* part = (float*)w; w += 128 * 64 * 4;
    (void)ws_size; (void)n_in; (void)out_size;

    // ---- CSR build ----
    hipMemsetAsync(deg, 0, (size_t)N * 4, stream);
    deg_count_kernel<<<(E + 255) / 256, 256, 0, stream>>>(ei, deg, E);
    scan_partial_kernel<<<NB, 256, 0, stream>>>(deg, bsum, N);
    scan_blocks_kernel<<<1, 256, 0, stream>>>(bsum, boff, rowptr + N, NB);
    scan_final_kernel<<<NB, 256, 0, stream>>>(deg, boff, rowptr, fill, N);
    scatter_kernel<<<(E + N + 255) / 256, 256, 0, stream>>>(ei, fill, col, E, N);
    // weight prep (merged)
    wprep_kernel<<<320, 256, 0, stream>>>(W2, W3, W2Th, W2Tl, W3Th, W3Tl);

    // ---- Layer 1: x[N,16] @ W1[16,256], fp32 VALU, C->bf16 ----
    gemm_attn_kernel<4><<<dim3((N + 63) / 64, 4), 256, 0, stream>>>(
        x, W1, Hb, a1s, a1d, es, ed, N, 16, 256);
    agg4_kernel<1, 2><<<(N + 3) / 4, 256, 0, stream>>>(Hb, es, ed, rowptr, col, b1, A1h, A1l, N);

    // ---- Layer 2: (A1h+A1l)[N,256] @ W2, split-bf16 MFMA ----
    gemm2_mfma_kernel<<<dim3((N + 127) / 128, 2), 256, 0, stream>>>(
        A1h, A1l, W2Th, W2Tl, Hb, a2s, a2d, es, ed, N);
    agg4_kernel<1, 1><<<(N + 3) / 4, 256, 0, stream>>>(Hb, es, ed, rowptr, col, b2, B0b, nullptr, N);

    // ---- Layer 3: B0b[N,256] @ W3, bf16-A MFMA ----
    gemm3_mfma_kernel<<<(N + 127) / 128, 256, 0, stream>>>(
        B0b, W3Th, W3Tl, H3b, a3s, a3d, es, ed, N);
    agg1_kernel<<<(N + 3) / 4, 256, 0, stream>>>(H3b, es, ed, rowptr, col, b3, out, N);

    // ---- graph mean ----
    gmean_partial<<<128, 256, 0, stream>>>(out, part, N);
    gmean_final<<<1, 64, 0, stream>>>(part, out + (size_t)N * 64, 128, 1.0f / N);
}

// Round 9
// 457.183 us; speedup vs baseline: 1.0241x; 1.0241x over previous
//
#include <hip/hip_runtime.h>
#include <math.h>

#define NNODES 50000

typedef __attribute__((ext_vector_type(8))) short short8;   // 8 bf16 (4 VGPRs)
typedef __attribute__((ext_vector_type(4))) float f32x4;    // MFMA accumulator

__device__ __forceinline__ unsigned short f2bf(float f) {
    unsigned u = __float_as_uint(f);
    u += 0x7fffu + ((u >> 16) & 1);   // RTN-even
    return (unsigned short)(u >> 16);
}
__device__ __forceinline__ float bf2f(unsigned short h) {
    return __uint_as_float(((unsigned)h) << 16);
}
__device__ __forceinline__ float bflo(unsigned u) { return __uint_as_float(u << 16); }
__device__ __forceinline__ float bfhi(unsigned u) { return __uint_as_float(u & 0xffff0000u); }

// ---------------- CSR build ----------------
// deg[] is zeroed via hipMemsetAsync; self-loop (+1) folded into the scan reads.
__global__ __launch_bounds__(256) void deg_count_kernel(const int* __restrict__ ei,
                                                        int* __restrict__ deg, int E) {
    int i = blockIdx.x * 256 + threadIdx.x;
    if (i < E) atomicAdd(&deg[ei[E + i]], 1);
}

__global__ __launch_bounds__(256) void scan_partial_kernel(const int* __restrict__ deg,
                                                           int* __restrict__ bsum, int N) {
    __shared__ int ls[256];
    int t = threadIdx.x;
    int i = blockIdx.x * 256 + t;
    ls[t] = (i < N) ? deg[i] + 1 : 0;   // +1 self-loop
    __syncthreads();
    #pragma unroll
    for (int off = 128; off; off >>= 1) {
        if (t < off) ls[t] += ls[t + off];
        __syncthreads();
    }
    if (t == 0) bsum[blockIdx.x] = ls[0];
}

__global__ __launch_bounds__(256) void scan_blocks_kernel(const int* __restrict__ bsum,
                                                          int* __restrict__ boff,
                                                          int* __restrict__ rowptrN, int nblk) {
    __shared__ int ls[256];
    int t = threadIdx.x;
    int v = (t < nblk) ? bsum[t] : 0;
    ls[t] = v;
    __syncthreads();
    for (int off = 1; off < 256; off <<= 1) {
        int u = (t >= off) ? ls[t - off] : 0;
        __syncthreads();
        ls[t] += u;
        __syncthreads();
    }
    if (t < nblk) boff[t] = ls[t] - v;
    if (t == 255) *rowptrN = ls[255];
}

__global__ __launch_bounds__(256) void scan_final_kernel(const int* __restrict__ deg,
                                                         const int* __restrict__ boff,
                                                         int* __restrict__ rowptr,
                                                         int* __restrict__ fill, int N) {
    __shared__ int ls[256];
    int t = threadIdx.x;
    int i = blockIdx.x * 256 + t;
    int v = (i < N) ? deg[i] + 1 : 0;   // +1 self-loop
    ls[t] = v;
    __syncthreads();
    for (int off = 1; off < 256; off <<= 1) {
        int u = (t >= off) ? ls[t - off] : 0;
        __syncthreads();
        ls[t] += u;
        __syncthreads();
    }
    if (i < N) {
        int e = boff[blockIdx.x] + ls[t] - v;
        rowptr[i] = e;
        fill[i] = e;
    }
}

__global__ __launch_bounds__(256) void scatter_kernel(const int* __restrict__ ei,
                                                      int* __restrict__ fill,
                                                      int* __restrict__ col, int E, int N) {
    int i = blockIdx.x * 256 + threadIdx.x;
    int total = E + N;
    if (i >= total) return;
    int s, d;
    if (i < E) { s = ei[i]; d = ei[E + i]; }
    else       { s = i - E; d = s; }
    int pos = atomicAdd(&fill[d], 1);
    col[pos] = s;
}

// ---------------- weight prep (merged): transpose + split fp32 -> bf16 hi/lo, [n][k] ----------------
__global__ __launch_bounds__(256) void wprep_kernel(const float* __restrict__ W2,
                                                    const float* __restrict__ W3,
                                                    unsigned short* __restrict__ W2Th,
                                                    unsigned short* __restrict__ W2Tl,
                                                    unsigned short* __restrict__ W3Th,
                                                    unsigned short* __restrict__ W3Tl) {
    int b = blockIdx.x;
    if (b < 256) {            // W2: 256x256
        int k = b, n = threadIdx.x;
        float w = W2[k * 256 + n];
        unsigned short h = f2bf(w);
        unsigned short l = f2bf(w - bf2f(h));
        W2Th[n * 256 + k] = h;
        W2Tl[n * 256 + k] = l;
    } else {                  // W3: 256x64 -> [64][256]
        int n = b - 256, k = threadIdx.x;
        float w = W3[k * 64 + n];
        unsigned short h = f2bf(w);
        unsigned short l = f2bf(w - bf2f(h));
        W3Th[n * 256 + k] = h;
        W3Tl[n * 256 + k] = l;
    }
}

#define LDK 40

// ---------------- layer-2 GEMM: split-bf16 MFMA, pre-split A, fused es/ed epilogue ----------------
__global__ __launch_bounds__(256) void gemm2_mfma_kernel(const unsigned short* __restrict__ Ahb,
                                                         const unsigned short* __restrict__ Alb,
                                                         const unsigned short* __restrict__ WTh,
                                                         const unsigned short* __restrict__ WTl,
                                                         unsigned short* __restrict__ Cb,
                                                         const float* __restrict__ as_,
                                                         const float* __restrict__ ad_,
                                                         float* __restrict__ es,
                                                         float* __restrict__ ed,
                                                         int M) {
    __shared__ __align__(16) unsigned short Ah[128][LDK], Al[128][LDK];
    __shared__ __align__(16) unsigned short Bh[128][LDK], Bl[128][LDK];
    int tid  = threadIdx.x;
    int lane = tid & 63, wave = tid >> 6;
    int wm = wave >> 1, wn = wave & 1;
    int bm = blockIdx.x * 128;
    int bn = blockIdx.y * 128;
    int c = lane & 15, q = lane >> 4;

    f32x4 acc[4][4] = {};

    for (int k0 = 0; k0 < 256; k0 += 32) {
        #pragma unroll
        for (int p = 0; p < 2; ++p) {
            int idx = p * 256 + tid;
            int r   = idx >> 2;
            int kc  = (idx & 3) * 8;
            int grow = bm + r;
            size_t go = (size_t)grow * 256 + k0 + kc;
            uint4 vh = make_uint4(0u,0u,0u,0u), vl = make_uint4(0u,0u,0u,0u);
            if (grow < M) {
                vh = *reinterpret_cast<const uint4*>(Ahb + go);
                vl = *reinterpret_cast<const uint4*>(Alb + go);
            }
            *reinterpret_cast<uint4*>(&Ah[r][kc]) = vh;
            *reinterpret_cast<uint4*>(&Al[r][kc]) = vl;
        }
        #pragma unroll
        for (int p = 0; p < 2; ++p) {
            int idx = p * 256 + tid;
            int n   = idx >> 2;
            int kc  = (idx & 3) * 8;
            const size_t go = (size_t)(bn + n) * 256 + k0 + kc;
            *reinterpret_cast<uint4*>(&Bh[n][kc]) = *reinterpret_cast<const uint4*>(WTh + go);
            *reinterpret_cast<uint4*>(&Bl[n][kc]) = *reinterpret_cast<const uint4*>(WTl + go);
        }
        __syncthreads();

        short8 bh[4], bl[4];
        #pragma unroll
        for (int nt = 0; nt < 4; ++nt) {
            bh[nt] = *reinterpret_cast<const short8*>(&Bh[wn * 64 + nt * 16 + c][q * 8]);
            bl[nt] = *reinterpret_cast<const short8*>(&Bl[wn * 64 + nt * 16 + c][q * 8]);
        }
        #pragma unroll
        for (int mt = 0; mt < 4; ++mt) {
            short8 ah = *reinterpret_cast<const short8*>(&Ah[wm * 64 + mt * 16 + c][q * 8]);
            short8 al = *reinterpret_cast<const short8*>(&Al[wm * 64 + mt * 16 + c][q * 8]);
            #pragma unroll
            for (int nt = 0; nt < 4; ++nt) {
                acc[mt][nt] = __builtin_amdgcn_mfma_f32_16x16x32_bf16(ah, bh[nt], acc[mt][nt], 0, 0, 0);
                acc[mt][nt] = __builtin_amdgcn_mfma_f32_16x16x32_bf16(ah, bl[nt], acc[mt][nt], 0, 0, 0);
                acc[mt][nt] = __builtin_amdgcn_mfma_f32_16x16x32_bf16(al, bh[nt], acc[mt][nt], 0, 0, 0);
            }
        }
        __syncthreads();
    }

    #pragma unroll
    for (int mt = 0; mt < 4; ++mt) {
        #pragma unroll
        for (int r = 0; r < 4; ++r) {
            int gr = bm + wm * 64 + mt * 16 + q * 4 + r;
            if (gr < M) {
                #pragma unroll
                for (int nt = 0; nt < 4; ++nt) {
                    Cb[(size_t)gr * 256 + bn + wn * 64 + nt * 16 + c] = f2bf(acc[mt][nt][r]);
                }
            }
        }
    }
    int head = blockIdx.y * 2 + wn;
    float asv[4], adv[4];
    #pragma unroll
    for (int nt = 0; nt < 4; ++nt) {
        asv[nt] = as_[head * 64 + nt * 16 + c];
        adv[nt] = ad_[head * 64 + nt * 16 + c];
    }
    #pragma unroll
    for (int mt = 0; mt < 4; ++mt) {
        #pragma unroll
        for (int r = 0; r < 4; ++r) {
            float s = 0.f, d = 0.f;
            #pragma unroll
            for (int nt = 0; nt < 4; ++nt) {
                s += acc[mt][nt][r] * asv[nt];
                d += acc[mt][nt][r] * adv[nt];
            }
            #pragma unroll
            for (int off = 1; off < 16; off <<= 1) {
                s += __shfl_xor(s, off, 64);
                d += __shfl_xor(d, off, 64);
            }
            int gr = bm + wm * 64 + mt * 16 + q * 4 + r;
            if (c == 0 && gr < M) {
                es[(size_t)gr * 4 + head] = s;
                ed[(size_t)gr * 4 + head] = d;
            }
        }
    }
}

// ---------------- layer-3 GEMM: bf16-A MFMA, W3 split hi/lo ----------------
__global__ __launch_bounds__(256) void gemm3_mfma_kernel(const unsigned short* __restrict__ Ab,
                                                         const unsigned short* __restrict__ WTh,
                                                         const unsigned short* __restrict__ WTl,
                                                         unsigned short* __restrict__ Cb,
                                                         const float* __restrict__ as_,
                                                         const float* __restrict__ ad_,
                                                         float* __restrict__ es,
                                                         float* __restrict__ ed,
                                                         int M) {
    __shared__ __align__(16) unsigned short Ah[128][LDK];
    __shared__ __align__(16) unsigned short Bh[64][LDK], Bl[64][LDK];
    int tid = threadIdx.x, lane = tid & 63, wave = tid >> 6;
    int bm = blockIdx.x * 128;
    int c = lane & 15, q = lane >> 4;
    f32x4 acc[2][4] = {};

    for (int k0 = 0; k0 < 256; k0 += 32) {
        #pragma unroll
        for (int p = 0; p < 2; ++p) {
            int idx = p * 256 + tid;
            int r   = idx >> 2;
            int kf  = (idx & 3) * 8;
            int grow = bm + r;
            uint4 v = (grow < M)
                ? *reinterpret_cast<const uint4*>(Ab + (size_t)grow * 256 + k0 + kf)
                : make_uint4(0u, 0u, 0u, 0u);
            *reinterpret_cast<uint4*>(&Ah[r][kf]) = v;
        }
        {
            int n  = tid >> 2;
            int kc = (tid & 3) * 8;
            size_t go = (size_t)n * 256 + k0 + kc;
            *reinterpret_cast<uint4*>(&Bh[n][kc]) = *reinterpret_cast<const uint4*>(WTh + go);
            *reinterpret_cast<uint4*>(&Bl[n][kc]) = *reinterpret_cast<const uint4*>(WTl + go);
        }
        __syncthreads();

        short8 bh[4], bl[4];
        #pragma unroll
        for (int nt = 0; nt < 4; ++nt) {
            bh[nt] = *reinterpret_cast<const short8*>(&Bh[nt * 16 + c][q * 8]);
            bl[nt] = *reinterpret_cast<const short8*>(&Bl[nt * 16 + c][q * 8]);
        }
        #pragma unroll
        for (int mt = 0; mt < 2; ++mt) {
            short8 a = *reinterpret_cast<const short8*>(&Ah[wave * 32 + mt * 16 + c][q * 8]);
            #pragma unroll
            for (int nt = 0; nt < 4; ++nt) {
                acc[mt][nt] = __builtin_amdgcn_mfma_f32_16x16x32_bf16(a, bh[nt], acc[mt][nt], 0, 0, 0);
                acc[mt][nt] = __builtin_amdgcn_mfma_f32_16x16x32_bf16(a, bl[nt], acc[mt][nt], 0, 0, 0);
            }
        }
        __syncthreads();
    }

    float asv[4], adv[4];
    #pragma unroll
    for (int nt = 0; nt < 4; ++nt) { asv[nt] = as_[nt * 16 + c]; adv[nt] = ad_[nt * 16 + c]; }
    #pragma unroll
    for (int mt = 0; mt < 2; ++mt) {
        #pragma unroll
        for (int r = 0; r < 4; ++r) {
            int gr = bm + wave * 32 + mt * 16 + q * 4 + r;
            bool ok = gr < M;
            if (ok) {
                #pragma unroll
                for (int nt = 0; nt < 4; ++nt)
                    Cb[(size_t)gr * 64 + nt * 16 + c] = f2bf(acc[mt][nt][r]);
            }
            float s = 0.f, d = 0.f;
            #pragma unroll
            for (int nt = 0; nt < 4; ++nt) {
                s += acc[mt][nt][r] * asv[nt];
                d += acc[mt][nt][r] * adv[nt];
            }
            #pragma unroll
            for (int off = 1; off < 16; off <<= 1) {
                s += __shfl_xor(s, off, 64);
                d += __shfl_xor(d, off, 64);
            }
            if (c == 0 && ok) { es[gr] = s; ed[gr] = d; }
        }
    }
}

// ---------------- layer-1 fp32 GEMM (K=16) with fused es/ed epilogue ----------------
template <int H>
__global__ __launch_bounds__(256) void gemm_attn_kernel(const float* __restrict__ A,
                                                        const float* __restrict__ B,
                                                        unsigned short* __restrict__ Cb,
                                                        const float* __restrict__ as_,
                                                        const float* __restrict__ ad_,
                                                        float* __restrict__ es,
                                                        float* __restrict__ ed,
                                                        int M, int K, int Ncol) {
    __shared__ __align__(16) float As[16][64];
    __shared__ __align__(16) float Bs[16][64];
    int tid = threadIdx.x;
    int bm = blockIdx.x * 64;
    int bn = blockIdx.y * 64;
    int tm = (tid >> 4) * 4;
    int tn = (tid & 15) * 4;
    float acc[4][4] = {};
    int ar  = tid >> 2;
    int akk = (tid & 3) * 4;
    int brr = tid >> 4;
    int bcc = (tid & 15) * 4;
    for (int k0 = 0; k0 < K; k0 += 16) {
        int grow = bm + ar;
        float4 av;
        if (grow < M) av = *reinterpret_cast<const float4*>(A + (size_t)grow * K + k0 + akk);
        else          av = make_float4(0.f, 0.f, 0.f, 0.f);
        As[akk + 0][ar] = av.x;
        As[akk + 1][ar] = av.y;
        As[akk + 2][ar] = av.z;
        As[akk + 3][ar] = av.w;
        float4 bv = *reinterpret_cast<const float4*>(B + (size_t)(k0 + brr) * Ncol + bn + bcc);
        *reinterpret_cast<float4*>(&Bs[brr][bcc]) = bv;
        __syncthreads();
        #pragma unroll
        for (int kk = 0; kk < 16; ++kk) {
            float4 a4 = *reinterpret_cast<const float4*>(&As[kk][tm]);
            float4 b4 = *reinterpret_cast<const float4*>(&Bs[kk][tn]);
            float a[4] = {a4.x, a4.y, a4.z, a4.w};
            float b[4] = {b4.x, b4.y, b4.z, b4.w};
            #pragma unroll
            for (int i = 0; i < 4; ++i)
                #pragma unroll
                for (int j = 0; j < 4; ++j) acc[i][j] += a[i] * b[j];
        }
        __syncthreads();
    }
    #pragma unroll
    for (int i = 0; i < 4; ++i) {
        int gr = bm + tm + i;
        if (gr < M) {
            ushort4 r;
            r.x = f2bf(acc[i][0]); r.y = f2bf(acc[i][1]);
            r.z = f2bf(acc[i][2]); r.w = f2bf(acc[i][3]);
            *reinterpret_cast<ushort4*>(Cb + (size_t)gr * Ncol + bn + tn) = r;
        }
    }
    int hy = blockIdx.y;
    float4 asv = *reinterpret_cast<const float4*>(as_ + (size_t)hy * 64 + tn);
    float4 adv = *reinterpret_cast<const float4*>(ad_ + (size_t)hy * 64 + tn);
    float sv[4], dv[4];
    #pragma unroll
    for (int i = 0; i < 4; ++i) {
        sv[i] = acc[i][0] * asv.x + acc[i][1] * asv.y + acc[i][2] * asv.z + acc[i][3] * asv.w;
        dv[i] = acc[i][0] * adv.x + acc[i][1] * adv.y + acc[i][2] * adv.z + acc[i][3] * adv.w;
    }
    #pragma unroll
    for (int off = 1; off < 16; off <<= 1) {
        #pragma unroll
        for (int i = 0; i < 4; ++i) {
            sv[i] += __shfl_xor(sv[i], off, 64);
            dv[i] += __shfl_xor(dv[i], off, 64);
        }
    }
    if ((tid & 15) == 0) {
        #pragma unroll
        for (int i = 0; i < 4; ++i) {
            int gr = bm + tm + i;
            if (gr < M) {
                es[(size_t)gr * H + hy] = sv[i];
                ed[(size_t)gr * H + hy] = dv[i];
            }
        }
    }
}

__device__ __forceinline__ float lrelu02(float x) { return x > 0.f ? x : 0.2f * x; }
__device__ __forceinline__ float eluf(float x)    { return x > 0.f ? x : expm1f(x); }

// ---------------- fused per-dst aggregation, H=4, bf16 gather, single-pass softmax ----------------
// Per-edge LDS entry packs (src, p_head) as uint2 -> one ds_read_b64 in the gather.
// den accumulated in-gather (identical values across a head group -> no reduce).
// Head stride 66 entries: base offsets differ by 132 dwords = 4 banks -> conflict-free.
// OUTMODE: 0 = fp32, 1 = bf16 (gemm3 A), 2 = pre-split hi/lo bf16 (gemm2 A).
template <int ACT, int OUTMODE>
__global__ __launch_bounds__(256) void agg4_kernel(const unsigned short* __restrict__ hb,
                                                   const float* __restrict__ es,
                                                   const float* __restrict__ ed,
                                                   const int* __restrict__ rowptr,
                                                   const int* __restrict__ col,
                                                   const float* __restrict__ bias,
                                                   void* __restrict__ outp,
                                                   void* __restrict__ outp2, int N) {
    __shared__ uint2 spds[4][4][66];   // [sub][head][edge] = (src, p)
    int sub  = threadIdx.x >> 6;
    int lane = threadIdx.x & 63;
    int node = blockIdx.x * 4 + sub;
    if (node >= N) return;
    int s = rowptr[node], t = rowptr[node + 1];

    float edv[4];
    #pragma unroll
    for (int h = 0; h < 4; ++h) edv[h] = ed[(size_t)node * 4 + h];

    int hh = lane >> 4;  // this lane's head (4 dims per lane)
    float den = 0.f;
    float4 acc = make_float4(0.f, 0.f, 0.f, 0.f);
    for (int base = s; base < t; base += 64) {
        int j = base + lane;
        int m = t - base; if (m > 64) m = 64;
        int sc = 0;
        float p[4] = {0.f, 0.f, 0.f, 0.f};
        if (j < t) {
            sc = col[j];
            float4 e4 = *reinterpret_cast<const float4*>(es + (size_t)sc * 4);
            p[0] = __expf(lrelu02(e4.x + edv[0]));
            p[1] = __expf(lrelu02(e4.y + edv[1]));
            p[2] = __expf(lrelu02(e4.z + edv[2]));
            p[3] = __expf(lrelu02(e4.w + edv[3]));
        }
        #pragma unroll
        for (int h = 0; h < 4; ++h)
            spds[sub][h][lane] = make_uint2((unsigned)sc, __float_as_uint(p[h]));
        #pragma unroll 4
        for (int jj = 0; jj < m; ++jj) {
            uint2 sp = spds[sub][hh][jj];       // broadcast within head group
            float a = __uint_as_float(sp.y);
            den += a;
            uint2 u = *reinterpret_cast<const uint2*>(hb + (size_t)sp.x * 256 + lane * 4);
            acc.x += bflo(u.x) * a;
            acc.y += bfhi(u.x) * a;
            acc.z += bflo(u.y) * a;
            acc.w += bfhi(u.y) * a;
        }
    }
    float inv = 1.f / den;
    float4 bv = *reinterpret_cast<const float4*>(bias + lane * 4);
    float r0 = acc.x * inv + bv.x;
    float r1 = acc.y * inv + bv.y;
    float r2 = acc.z * inv + bv.z;
    float r3 = acc.w * inv + bv.w;
    if (ACT) { r0 = eluf(r0); r1 = eluf(r1); r2 = eluf(r2); r3 = eluf(r3); }
    if constexpr (OUTMODE == 0) {
        *reinterpret_cast<float4*>((float*)outp + (size_t)node * 256 + lane * 4) =
            make_float4(r0, r1, r2, r3);
    } else if constexpr (OUTMODE == 1) {
        ushort4 o;
        o.x = f2bf(r0); o.y = f2bf(r1); o.z = f2bf(r2); o.w = f2bf(r3);
        *reinterpret_cast<ushort4*>((unsigned short*)outp + (size_t)node * 256 + lane * 4) = o;
    } else {
        ushort4 oh, ol;
        oh.x = f2bf(r0); ol.x = f2bf(r0 - bf2f(oh.x));
        oh.y = f2bf(r1); ol.y = f2bf(r1 - bf2f(oh.y));
        oh.z = f2bf(r2); ol.z = f2bf(r2 - bf2f(oh.z));
        oh.w = f2bf(r3); ol.w = f2bf(r3 - bf2f(oh.w));
        size_t o = (size_t)node * 256 + lane * 4;
        *reinterpret_cast<ushort4*>((unsigned short*)outp  + o) = oh;
        *reinterpret_cast<ushort4*>((unsigned short*)outp2 + o) = ol;
    }
}

// ---------------- fused per-dst aggregation, H=1, bf16 gather, half-wave uint loads ----------------
// 32 lanes x 2 dims, 2 edges per wave-iter; (src,p) packed uint2 in LDS; den in-gather
// per half, combined with one shfl_xor(32).
__global__ __launch_bounds__(256) void agg1_kernel(const unsigned short* __restrict__ hb,
                                                   const float* __restrict__ es,
                                                   const float* __restrict__ ed,
                                                   const int* __restrict__ rowptr,
                                                   const int* __restrict__ col,
                                                   const float* __restrict__ bias,
                                                   float* __restrict__ out, int N) {
    __shared__ uint2 spds[4][66];
    int sub  = threadIdx.x >> 6;
    int lane = threadIdx.x & 63;
    int node = blockIdx.x * 4 + sub;
    if (node >= N) return;
    int s = rowptr[node], t = rowptr[node + 1];
    float edv = ed[node];

    int half = lane >> 5, sl = lane & 31;
    float den = 0.f, acc0 = 0.f, acc1 = 0.f;   // dims sl*2, sl*2+1
    for (int base = s; base < t; base += 64) {
        int j = base + lane;
        int m = t - base; if (m > 64) m = 64;
        int sc = 0;
        float p0 = 0.f;
        if (j < t) {
            sc = col[j];
            p0 = __expf(lrelu02(es[sc] + edv));
        }
        spds[sub][lane] = make_uint2((unsigned)sc, __float_as_uint(p0));
        int nit = (m + 1) >> 1;
        #pragma unroll 4
        for (int it = 0; it < nit; ++it) {
            int idx = 2 * it + half;          // phantom odd edge has p=0 (safe)
            uint2 sp = spds[sub][idx];
            float a = __uint_as_float(sp.y);
            den += a;
            unsigned u = *reinterpret_cast<const unsigned*>(hb + (size_t)sp.x * 64 + sl * 2);
            acc0 += bflo(u) * a;
            acc1 += bfhi(u) * a;
        }
    }
    acc0 += __shfl_xor(acc0, 32, 64);
    acc1 += __shfl_xor(acc1, 32, 64);
    den  += __shfl_xor(den, 32, 64);
    if (half == 0) {
        float inv = 1.f / den;
        float2 b = *reinterpret_cast<const float2*>(bias + sl * 2);
        *reinterpret_cast<float2*>(out + (size_t)node * 64 + sl * 2) =
            make_float2(acc0 * inv + b.x, acc1 * inv + b.y);
    }
}

// ---------------- graph mean ----------------
__global__ __launch_bounds__(256) void gmean_partial(const float* __restrict__ ne,
                                                     float* __restrict__ part, int N) {
    int d = threadIdx.x & 63, sub = threadIdx.x >> 6;
    int start = blockIdx.x * 4 + sub;
    float s = 0.f;
    for (int n = start; n < N; n += gridDim.x * 4) s += ne[(size_t)n * 64 + d];
    __shared__ float ls[256];
    ls[threadIdx.x] = s;
    __syncthreads();
    if (threadIdx.x < 64) {
        float v = ls[threadIdx.x] + ls[threadIdx.x + 64] + ls[threadIdx.x + 128] + ls[threadIdx.x + 192];
        part[blockIdx.x * 64 + d] = v;
    }
}

__global__ __launch_bounds__(64) void gmean_final(const float* __restrict__ part,
                                                  float* __restrict__ gout, int nblk, float invN) {
    int d = threadIdx.x;
    float s = 0.f;
    for (int b = 0; b < nblk; ++b) s += part[b * 64 + d];
    gout[d] = s * invN;
}

extern "C" void kernel_launch(void* const* d_in, const int* in_sizes, int n_in,
                              void* d_out, int out_size, void* d_ws, size_t ws_size,
                              hipStream_t stream) {
    const float* x   = (const float*)d_in[0];
    const int*   ei  = (const int*)d_in[1];
    const float* W1  = (const float*)d_in[2];
    const float* a1s = (const float*)d_in[3];
    const float* a1d = (const float*)d_in[4];
    const float* b1  = (const float*)d_in[5];
    const float* W2  = (const float*)d_in[6];
    const float* a2s = (const float*)d_in[7];
    const float* a2d = (const float*)d_in[8];
    const float* b2  = (const float*)d_in[9];
    const float* W3  = (const float*)d_in[10];
    const float* a3s = (const float*)d_in[11];
    const float* a3d = (const float*)d_in[12];
    const float* b3  = (const float*)d_in[13];
    float* out = (float*)d_out;

    const int N = NNODES;
    const int E = in_sizes[1] / 2;  // 800000
    const int NB = (N + 255) / 256;

    // workspace carve (16B alignment maintained)
    char* w = (char*)d_ws;
    unsigned short* Hb   = (unsigned short*)w; w += (size_t)N * 256 * 2;  // h1/h2 bf16 (agg4 gather)
    unsigned short* B0b  = (unsigned short*)w; w += (size_t)N * 256 * 2;  // agg2 out bf16 (gemm3 A)
    unsigned short* H3b  = (unsigned short*)w; w += (size_t)N * 64 * 2;   // h3 bf16 (agg1 gather)
    unsigned short* A1h  = (unsigned short*)w; w += (size_t)N * 256 * 2;  // agg1(layer1) out hi (gemm2 A)
    unsigned short* A1l  = (unsigned short*)w; w += (size_t)N * 256 * 2;  // agg1(layer1) out lo
    float* es = (float*)w; w += (size_t)N * 4 * 4;
    float* ed = (float*)w; w += (size_t)N * 4 * 4;
    unsigned short* W2Th = (unsigned short*)w; w += 256 * 256 * 2;
    unsigned short* W2Tl = (unsigned short*)w; w += 256 * 256 * 2;
    unsigned short* W3Th = (unsigned short*)w; w += 64 * 256 * 2;
    unsigned short* W3Tl = (unsigned short*)w; w += 64 * 256 * 2;
    int* deg    = (int*)w; w += (size_t)N * 4;
    int* rowptr = (int*)w; w += (size_t)(N + 2) * 4;
    int* fill   = (int*)w; w += (size_t)N * 4;
    int* col    = (int*)w; w += (size_t)(E + N) * 4;
    int* bsum   = (int*)w; w += 256 * 4;
    int* boff   = (int*)w; w += 256 * 4;
    float* part = (float*)w; w += 128 * 64 * 4;
    (void)ws_size; (void)n_in; (void)out_size;

    // ---- CSR build ----
    hipMemsetAsync(deg, 0, (size_t)N * 4, stream);
    deg_count_kernel<<<(E + 255) / 256, 256, 0, stream>>>(ei, deg, E);
    scan_partial_kernel<<<NB, 256, 0, stream>>>(deg, bsum, N);
    scan_blocks_kernel<<<1, 256, 0, stream>>>(bsum, boff, rowptr + N, NB);
    scan_final_kernel<<<NB, 256, 0, stream>>>(deg, boff, rowptr, fill, N);
    scatter_kernel<<<(E + N + 255) / 256, 256, 0, stream>>>(ei, fill, col, E, N);
    // weight prep (merged)
    wprep_kernel<<<320, 256, 0, stream>>>(W2, W3, W2Th, W2Tl, W3Th, W3Tl);

    // ---- Layer 1: x[N,16] @ W1[16,256], fp32 VALU, C->bf16 ----
    gemm_attn_kernel<4><<<dim3((N + 63) / 64, 4), 256, 0, stream>>>(
        x, W1, Hb, a1s, a1d, es, ed, N, 16, 256);
    agg4_kernel<1, 2><<<(N + 3) / 4, 256, 0, stream>>>(Hb, es, ed, rowptr, col, b1, A1h, A1l, N);

    // ---- Layer 2: (A1h+A1l)[N,256] @ W2, split-bf16 MFMA ----
    gemm2_mfma_kernel<<<dim3((N + 127) / 128, 2), 256, 0, stream>>>(
        A1h, A1l, W2Th, W2Tl, Hb, a2s, a2d, es, ed, N);
    agg4_kernel<1, 1><<<(N + 3) / 4, 256, 0, stream>>>(Hb, es, ed, rowptr, col, b2, B0b, nullptr, N);

    // ---- Layer 3: B0b[N,256] @ W3, bf16-A MFMA ----
    gemm3_mfma_kernel<<<(N + 127) / 128, 256, 0, stream>>>(
        B0b, W3Th, W3Tl, H3b, a3s, a3d, es, ed, N);
    agg1_kernel<<<(N + 3) / 4, 256, 0, stream>>>(H3b, es, ed, rowptr, col, b3, out, N);

    // ---- graph mean ----
    gmean_partial<<<128, 256, 0, stream>>>(out, part, N);
    gmean_final<<<1, 64, 0, stream>>>(part, out + (size_t)N * 64, 128, 1.0f / N);
}

// Round 10
// 428.500 us; speedup vs baseline: 1.0926x; 1.0669x over previous
//
#include <hip/hip_runtime.h>
#include <math.h>

#define NNODES 50000

typedef __attribute__((ext_vector_type(8))) short short8;   // 8 bf16 (4 VGPRs)
typedef __attribute__((ext_vector_type(4))) float f32x4;    // MFMA accumulator

__device__ __forceinline__ unsigned short f2bf(float f) {
    unsigned u = __float_as_uint(f);
    u += 0x7fffu + ((u >> 16) & 1);   // RTN-even
    return (unsigned short)(u >> 16);
}
__device__ __forceinline__ float bf2f(unsigned short h) {
    return __uint_as_float(((unsigned)h) << 16);
}
__device__ __forceinline__ float bflo(unsigned u) { return __uint_as_float(u << 16); }
__device__ __forceinline__ float bfhi(unsigned u) { return __uint_as_float(u & 0xffff0000u); }

// ---------------- CSR build ----------------
__global__ __launch_bounds__(256) void deg_count_kernel(const int* __restrict__ ei,
                                                        int* __restrict__ deg, int E) {
    int i = blockIdx.x * 256 + threadIdx.x;
    if (i < E) atomicAdd(&deg[ei[E + i]], 1);
}

__global__ __launch_bounds__(256) void scan_partial_kernel(const int* __restrict__ deg,
                                                           int* __restrict__ bsum, int N) {
    __shared__ int ls[256];
    int t = threadIdx.x;
    int i = blockIdx.x * 256 + t;
    ls[t] = (i < N) ? deg[i] + 1 : 0;   // +1 self-loop
    __syncthreads();
    #pragma unroll
    for (int off = 128; off; off >>= 1) {
        if (t < off) ls[t] += ls[t + off];
        __syncthreads();
    }
    if (t == 0) bsum[blockIdx.x] = ls[0];
}

__global__ __launch_bounds__(256) void scan_blocks_kernel(const int* __restrict__ bsum,
                                                          int* __restrict__ boff,
                                                          int* __restrict__ rowptrN, int nblk) {
    __shared__ int ls[256];
    int t = threadIdx.x;
    int v = (t < nblk) ? bsum[t] : 0;
    ls[t] = v;
    __syncthreads();
    for (int off = 1; off < 256; off <<= 1) {
        int u = (t >= off) ? ls[t - off] : 0;
        __syncthreads();
        ls[t] += u;
        __syncthreads();
    }
    if (t < nblk) boff[t] = ls[t] - v;
    if (t == 255) *rowptrN = ls[255];
}

__global__ __launch_bounds__(256) void scan_final_kernel(const int* __restrict__ deg,
                                                         const int* __restrict__ boff,
                                                         int* __restrict__ rowptr,
                                                         int* __restrict__ fill, int N) {
    __shared__ int ls[256];
    int t = threadIdx.x;
    int i = blockIdx.x * 256 + t;
    int v = (i < N) ? deg[i] + 1 : 0;   // +1 self-loop
    ls[t] = v;
    __syncthreads();
    for (int off = 1; off < 256; off <<= 1) {
        int u = (t >= off) ? ls[t - off] : 0;
        __syncthreads();
        ls[t] += u;
        __syncthreads();
    }
    if (i < N) {
        int e = boff[blockIdx.x] + ls[t] - v;
        rowptr[i] = e;
        fill[i] = e;
    }
}

__global__ __launch_bounds__(256) void scatter_kernel(const int* __restrict__ ei,
                                                      int* __restrict__ fill,
                                                      int* __restrict__ col, int E, int N) {
    int i = blockIdx.x * 256 + threadIdx.x;
    int total = E + N;
    if (i >= total) return;
    int s, d;
    if (i < E) { s = ei[i]; d = ei[E + i]; }
    else       { s = i - E; d = s; }
    int pos = atomicAdd(&fill[d], 1);
    col[pos] = s;
}

// ---------------- weight prep: W2/W3 transpose+split; w1s/w1d = W1^T a1s/a1d ----------------
__global__ __launch_bounds__(256) void wprep_kernel(const float* __restrict__ W1,
                                                    const float* __restrict__ a1s,
                                                    const float* __restrict__ a1d,
                                                    const float* __restrict__ W2,
                                                    const float* __restrict__ W3,
                                                    unsigned short* __restrict__ W2Th,
                                                    unsigned short* __restrict__ W2Tl,
                                                    unsigned short* __restrict__ W3Th,
                                                    unsigned short* __restrict__ W3Tl,
                                                    float* __restrict__ w1s,
                                                    float* __restrict__ w1d) {
    int b = blockIdx.x;
    if (b < 256) {            // W2: 256x256
        int k = b, n = threadIdx.x;
        float w = W2[k * 256 + n];
        unsigned short h = f2bf(w);
        unsigned short l = f2bf(w - bf2f(h));
        W2Th[n * 256 + k] = h;
        W2Tl[n * 256 + k] = l;
    } else if (b < 320) {     // W3: 256x64 -> [64][256]
        int n = b - 256, k = threadIdx.x;
        float w = W3[k * 64 + n];
        unsigned short h = f2bf(w);
        unsigned short l = f2bf(w - bf2f(h));
        W3Th[n * 256 + k] = h;
        W3Tl[n * 256 + k] = l;
    } else {                  // w1s[h*16+k] = sum_d W1[k][h*64+d]*a1s[h*64+d]
        int t = threadIdx.x;
        if (t < 128) {
            int which = t >> 6;           // 0: w1s, 1: w1d
            int hk = t & 63;
            int h = hk >> 4, k = hk & 15;
            const float* av = which ? a1d : a1s;
            float s = 0.f;
            for (int d = 0; d < 64; ++d)
                s += W1[k * 256 + h * 64 + d] * av[h * 64 + d];
            (which ? w1d : w1s)[hk] = s;
        }
    }
}

// ---------------- layer-1 attention coefficients: es1/ed1 = x . w1s/w1d ----------------
__global__ __launch_bounds__(256) void esed1_kernel(const float* __restrict__ x,
                                                    const float* __restrict__ w1s,
                                                    const float* __restrict__ w1d,
                                                    float* __restrict__ es,
                                                    float* __restrict__ ed, int N) {
    int i = blockIdx.x * 256 + threadIdx.x;
    if (i >= N) return;
    float xv[16];
    #pragma unroll
    for (int p = 0; p < 4; ++p) {
        float4 v = *reinterpret_cast<const float4*>(x + (size_t)i * 16 + p * 4);
        xv[p * 4 + 0] = v.x; xv[p * 4 + 1] = v.y; xv[p * 4 + 2] = v.z; xv[p * 4 + 3] = v.w;
    }
    float4 se, de;
    float* sp = &se.x; float* dp = &de.x;
    #pragma unroll
    for (int h = 0; h < 4; ++h) {
        float s = 0.f, d = 0.f;
        #pragma unroll
        for (int k = 0; k < 16; ++k) {
            s += xv[k] * w1s[h * 16 + k];
            d += xv[k] * w1d[h * 16 + k];
        }
        sp[h] = s; dp[h] = d;
    }
    *reinterpret_cast<float4*>(es + (size_t)i * 4) = se;
    *reinterpret_cast<float4*>(ed + (size_t)i * 4) = de;
}

__device__ __forceinline__ float lrelu02(float x) { return x > 0.f ? x : 0.2f * x; }
__device__ __forceinline__ float eluf(float x)    { return x > 0.f ? x : expm1f(x); }

// ---------------- layer-1 x-space aggregation ----------------
// zn[dst][h][d16] = (Sum_e p[e,h] * x[src_e][d]) / den[h].   Quarter-wave per edge:
// lane = (eg<<4)|d, 4 edges per gather inst, 1 cache line per x row (64 B aligned).
__global__ __launch_bounds__(256) void aggx_kernel(const float* __restrict__ x,
                                                   const float* __restrict__ es,
                                                   const float* __restrict__ ed,
                                                   const int* __restrict__ rowptr,
                                                   const int* __restrict__ col,
                                                   float* __restrict__ zn, int N) {
    __shared__ int    slds[4][64];
    __shared__ float4 plds[4][64];
    int sub  = threadIdx.x >> 6;
    int lane = threadIdx.x & 63;
    int node = blockIdx.x * 4 + sub;
    if (node >= N) return;
    int s = rowptr[node], t = rowptr[node + 1];

    float edv[4];
    #pragma unroll
    for (int h = 0; h < 4; ++h) edv[h] = ed[(size_t)node * 4 + h];

    int eg = lane >> 4, d = lane & 15;
    float acc[4] = {0.f, 0.f, 0.f, 0.f};
    float den[4] = {0.f, 0.f, 0.f, 0.f};

    for (int base = s; base < t; base += 64) {
        int j = base + lane;
        int m = t - base; if (m > 64) m = 64;
        int sc = 0;
        float4 p = make_float4(0.f, 0.f, 0.f, 0.f);
        if (j < t) {
            sc = col[j];
            float4 e4 = *reinterpret_cast<const float4*>(es + (size_t)sc * 4);
            p.x = __expf(lrelu02(e4.x + edv[0]));
            p.y = __expf(lrelu02(e4.y + edv[1]));
            p.z = __expf(lrelu02(e4.z + edv[2]));
            p.w = __expf(lrelu02(e4.w + edv[3]));
        }
        slds[sub][lane] = sc;
        plds[sub][lane] = p;
        int nit = (m + 3) >> 2;
        #pragma unroll 4
        for (int it = 0; it < nit; ++it) {
            int e = it * 4 + eg;             // phantom edges have p=0 (all 64 slots written)
            int scj = slds[sub][e];
            float4 pj = plds[sub][e];
            float xv = x[(size_t)scj * 16 + d];
            acc[0] += pj.x * xv; acc[1] += pj.y * xv;
            acc[2] += pj.z * xv; acc[3] += pj.w * xv;
            den[0] += pj.x; den[1] += pj.y; den[2] += pj.z; den[3] += pj.w;
        }
    }
    // combine the 4 edge-groups (den identical within a group -> each group counted once)
    #pragma unroll
    for (int h = 0; h < 4; ++h) {
        acc[h] += __shfl_xor(acc[h], 16, 64);
        acc[h] += __shfl_xor(acc[h], 32, 64);
        den[h] += __shfl_xor(den[h], 16, 64);
        den[h] += __shfl_xor(den[h], 32, 64);
    }
    // lane l -> h = eg, dim = d: zn[node*64 + h*16 + d] == zn[node*64 + lane]
    float a = (eg == 0) ? acc[0] : (eg == 1) ? acc[1] : (eg == 2) ? acc[2] : acc[3];
    float dn = (eg == 0) ? den[0] : (eg == 1) ? den[1] : (eg == 2) ? den[2] : den[3];
    zn[(size_t)node * 64 + lane] = a / dn;
}

// ---------------- layer-1 GEMM on aggregated z: h1' = elu(zn.W1 + b1), hi/lo-split out ----------------
// A = zn[M,64] (head hy uses cols hy*16..+15, K=16); B = W1[16,256] (head slab hy*64).
__global__ __launch_bounds__(256) void gemm1z_kernel(const float* __restrict__ zn,
                                                     const float* __restrict__ W1,
                                                     const float* __restrict__ b1,
                                                     unsigned short* __restrict__ A1h,
                                                     unsigned short* __restrict__ A1l,
                                                     int M) {
    __shared__ __align__(16) float As[16][64];
    __shared__ __align__(16) float Bs[16][64];
    int tid = threadIdx.x;
    int bm = blockIdx.x * 64;
    int hy = blockIdx.y;
    int tm = (tid >> 4) * 4;
    int tn = (tid & 15) * 4;
    float acc[4][4] = {};
    int ar  = tid >> 2;          // row 0..63
    int akk = (tid & 3) * 4;     // k 0,4,8,12
    int brr = tid >> 4;          // k 0..15
    int bcc = (tid & 15) * 4;    // n
    {
        int grow = bm + ar;
        float4 av = (grow < M)
            ? *reinterpret_cast<const float4*>(zn + (size_t)grow * 64 + hy * 16 + akk)
            : make_float4(0.f, 0.f, 0.f, 0.f);
        As[akk + 0][ar] = av.x;
        As[akk + 1][ar] = av.y;
        As[akk + 2][ar] = av.z;
        As[akk + 3][ar] = av.w;
        float4 bv = *reinterpret_cast<const float4*>(W1 + (size_t)brr * 256 + hy * 64 + bcc);
        *reinterpret_cast<float4*>(&Bs[brr][bcc]) = bv;
        __syncthreads();
        #pragma unroll
        for (int kk = 0; kk < 16; ++kk) {
            float4 a4 = *reinterpret_cast<const float4*>(&As[kk][tm]);
            float4 b4 = *reinterpret_cast<const float4*>(&Bs[kk][tn]);
            float a[4] = {a4.x, a4.y, a4.z, a4.w};
            float b[4] = {b4.x, b4.y, b4.z, b4.w};
            #pragma unroll
            for (int i = 0; i < 4; ++i)
                #pragma unroll
                for (int j = 0; j < 4; ++j) acc[i][j] += a[i] * b[j];
        }
    }
    float4 bb = *reinterpret_cast<const float4*>(b1 + hy * 64 + tn);
    #pragma unroll
    for (int i = 0; i < 4; ++i) {
        int gr = bm + tm + i;
        if (gr < M) {
            float r0 = eluf(acc[i][0] + bb.x);
            float r1 = eluf(acc[i][1] + bb.y);
            float r2 = eluf(acc[i][2] + bb.z);
            float r3 = eluf(acc[i][3] + bb.w);
            ushort4 oh, ol;
            oh.x = f2bf(r0); ol.x = f2bf(r0 - bf2f(oh.x));
            oh.y = f2bf(r1); ol.y = f2bf(r1 - bf2f(oh.y));
            oh.z = f2bf(r2); ol.z = f2bf(r2 - bf2f(oh.z));
            oh.w = f2bf(r3); ol.w = f2bf(r3 - bf2f(oh.w));
            size_t o = (size_t)gr * 256 + hy * 64 + tn;
            *reinterpret_cast<ushort4*>(A1h + o) = oh;
            *reinterpret_cast<ushort4*>(A1l + o) = ol;
        }
    }
}

#define LDK 40

// ---------------- layer-2 GEMM: split-bf16 MFMA, pre-split A, fused es/ed epilogue ----------------
__global__ __launch_bounds__(256) void gemm2_mfma_kernel(const unsigned short* __restrict__ Ahb,
                                                         const unsigned short* __restrict__ Alb,
                                                         const unsigned short* __restrict__ WTh,
                                                         const unsigned short* __restrict__ WTl,
                                                         unsigned short* __restrict__ Cb,
                                                         const float* __restrict__ as_,
                                                         const float* __restrict__ ad_,
                                                         float* __restrict__ es,
                                                         float* __restrict__ ed,
                                                         int M) {
    __shared__ __align__(16) unsigned short Ah[128][LDK], Al[128][LDK];
    __shared__ __align__(16) unsigned short Bh[128][LDK], Bl[128][LDK];
    int tid  = threadIdx.x;
    int lane = tid & 63, wave = tid >> 6;
    int wm = wave >> 1, wn = wave & 1;
    int bm = blockIdx.x * 128;
    int bn = blockIdx.y * 128;
    int c = lane & 15, q = lane >> 4;

    f32x4 acc[4][4] = {};

    for (int k0 = 0; k0 < 256; k0 += 32) {
        #pragma unroll
        for (int p = 0; p < 2; ++p) {
            int idx = p * 256 + tid;
            int r   = idx >> 2;
            int kc  = (idx & 3) * 8;
            int grow = bm + r;
            size_t go = (size_t)grow * 256 + k0 + kc;
            uint4 vh = make_uint4(0u,0u,0u,0u), vl = make_uint4(0u,0u,0u,0u);
            if (grow < M) {
                vh = *reinterpret_cast<const uint4*>(Ahb + go);
                vl = *reinterpret_cast<const uint4*>(Alb + go);
            }
            *reinterpret_cast<uint4*>(&Ah[r][kc]) = vh;
            *reinterpret_cast<uint4*>(&Al[r][kc]) = vl;
        }
        #pragma unroll
        for (int p = 0; p < 2; ++p) {
            int idx = p * 256 + tid;
            int n   = idx >> 2;
            int kc  = (idx & 3) * 8;
            const size_t go = (size_t)(bn + n) * 256 + k0 + kc;
            *reinterpret_cast<uint4*>(&Bh[n][kc]) = *reinterpret_cast<const uint4*>(WTh + go);
            *reinterpret_cast<uint4*>(&Bl[n][kc]) = *reinterpret_cast<const uint4*>(WTl + go);
        }
        __syncthreads();

        short8 bh[4], bl[4];
        #pragma unroll
        for (int nt = 0; nt < 4; ++nt) {
            bh[nt] = *reinterpret_cast<const short8*>(&Bh[wn * 64 + nt * 16 + c][q * 8]);
            bl[nt] = *reinterpret_cast<const short8*>(&Bl[wn * 64 + nt * 16 + c][q * 8]);
        }
        #pragma unroll
        for (int mt = 0; mt < 4; ++mt) {
            short8 ah = *reinterpret_cast<const short8*>(&Ah[wm * 64 + mt * 16 + c][q * 8]);
            short8 al = *reinterpret_cast<const short8*>(&Al[wm * 64 + mt * 16 + c][q * 8]);
            #pragma unroll
            for (int nt = 0; nt < 4; ++nt) {
                acc[mt][nt] = __builtin_amdgcn_mfma_f32_16x16x32_bf16(ah, bh[nt], acc[mt][nt], 0, 0, 0);
                acc[mt][nt] = __builtin_amdgcn_mfma_f32_16x16x32_bf16(ah, bl[nt], acc[mt][nt], 0, 0, 0);
                acc[mt][nt] = __builtin_amdgcn_mfma_f32_16x16x32_bf16(al, bh[nt], acc[mt][nt], 0, 0, 0);
            }
        }
        __syncthreads();
    }

    #pragma unroll
    for (int mt = 0; mt < 4; ++mt) {
        #pragma unroll
        for (int r = 0; r < 4; ++r) {
            int gr = bm + wm * 64 + mt * 16 + q * 4 + r;
            if (gr < M) {
                #pragma unroll
                for (int nt = 0; nt < 4; ++nt) {
                    Cb[(size_t)gr * 256 + bn + wn * 64 + nt * 16 + c] = f2bf(acc[mt][nt][r]);
                }
            }
        }
    }
    int head = blockIdx.y * 2 + wn;
    float asv[4], adv[4];
    #pragma unroll
    for (int nt = 0; nt < 4; ++nt) {
        asv[nt] = as_[head * 64 + nt * 16 + c];
        adv[nt] = ad_[head * 64 + nt * 16 + c];
    }
    #pragma unroll
    for (int mt = 0; mt < 4; ++mt) {
        #pragma unroll
        for (int r = 0; r < 4; ++r) {
            float s = 0.f, d = 0.f;
            #pragma unroll
            for (int nt = 0; nt < 4; ++nt) {
                s += acc[mt][nt][r] * asv[nt];
                d += acc[mt][nt][r] * adv[nt];
            }
            #pragma unroll
            for (int off = 1; off < 16; off <<= 1) {
                s += __shfl_xor(s, off, 64);
                d += __shfl_xor(d, off, 64);
            }
            int gr = bm + wm * 64 + mt * 16 + q * 4 + r;
            if (c == 0 && gr < M) {
                es[(size_t)gr * 4 + head] = s;
                ed[(size_t)gr * 4 + head] = d;
            }
        }
    }
}

// ---------------- layer-3 GEMM: bf16-A MFMA, W3 split hi/lo ----------------
__global__ __launch_bounds__(256) void gemm3_mfma_kernel(const unsigned short* __restrict__ Ab,
                                                         const unsigned short* __restrict__ WTh,
                                                         const unsigned short* __restrict__ WTl,
                                                         unsigned short* __restrict__ Cb,
                                                         const float* __restrict__ as_,
                                                         const float* __restrict__ ad_,
                                                         float* __restrict__ es,
                                                         float* __restrict__ ed,
                                                         int M) {
    __shared__ __align__(16) unsigned short Ah[128][LDK];
    __shared__ __align__(16) unsigned short Bh[64][LDK], Bl[64][LDK];
    int tid = threadIdx.x, lane = tid & 63, wave = tid >> 6;
    int bm = blockIdx.x * 128;
    int c = lane & 15, q = lane >> 4;
    f32x4 acc[2][4] = {};

    for (int k0 = 0; k0 < 256; k0 += 32) {
        #pragma unroll
        for (int p = 0; p < 2; ++p) {
            int idx = p * 256 + tid;
            int r   = idx >> 2;
            int kf  = (idx & 3) * 8;
            int grow = bm + r;
            uint4 v = (grow < M)
                ? *reinterpret_cast<const uint4*>(Ab + (size_t)grow * 256 + k0 + kf)
                : make_uint4(0u, 0u, 0u, 0u);
            *reinterpret_cast<uint4*>(&Ah[r][kf]) = v;
        }
        {
            int n  = tid >> 2;
            int kc = (tid & 3) * 8;
            size_t go = (size_t)n * 256 + k0 + kc;
            *reinterpret_cast<uint4*>(&Bh[n][kc]) = *reinterpret_cast<const uint4*>(WTh + go);
            *reinterpret_cast<uint4*>(&Bl[n][kc]) = *reinterpret_cast<const uint4*>(WTl + go);
        }
        __syncthreads();

        short8 bh[4], bl[4];
        #pragma unroll
        for (int nt = 0; nt < 4; ++nt) {
            bh[nt] = *reinterpret_cast<const short8*>(&Bh[nt * 16 + c][q * 8]);
            bl[nt] = *reinterpret_cast<const short8*>(&Bl[nt * 16 + c][q * 8]);
        }
        #pragma unroll
        for (int mt = 0; mt < 2; ++mt) {
            short8 a = *reinterpret_cast<const short8*>(&Ah[wave * 32 + mt * 16 + c][q * 8]);
            #pragma unroll
            for (int nt = 0; nt < 4; ++nt) {
                acc[mt][nt] = __builtin_amdgcn_mfma_f32_16x16x32_bf16(a, bh[nt], acc[mt][nt], 0, 0, 0);
                acc[mt][nt] = __builtin_amdgcn_mfma_f32_16x16x32_bf16(a, bl[nt], acc[mt][nt], 0, 0, 0);
            }
        }
        __syncthreads();
    }

    float asv[4], adv[4];
    #pragma unroll
    for (int nt = 0; nt < 4; ++nt) { asv[nt] = as_[nt * 16 + c]; adv[nt] = ad_[nt * 16 + c]; }
    #pragma unroll
    for (int mt = 0; mt < 2; ++mt) {
        #pragma unroll
        for (int r = 0; r < 4; ++r) {
            int gr = bm + wave * 32 + mt * 16 + q * 4 + r;
            bool ok = gr < M;
            if (ok) {
                #pragma unroll
                for (int nt = 0; nt < 4; ++nt)
                    Cb[(size_t)gr * 64 + nt * 16 + c] = f2bf(acc[mt][nt][r]);
            }
            float s = 0.f, d = 0.f;
            #pragma unroll
            for (int nt = 0; nt < 4; ++nt) {
                s += acc[mt][nt][r] * asv[nt];
                d += acc[mt][nt][r] * adv[nt];
            }
            #pragma unroll
            for (int off = 1; off < 16; off <<= 1) {
                s += __shfl_xor(s, off, 64);
                d += __shfl_xor(d, off, 64);
            }
            if (c == 0 && ok) { es[gr] = s; ed[gr] = d; }
        }
    }
}

// ---------------- fused per-dst aggregation, H=4, bf16 gather, single-pass softmax ----------------
template <int ACT, int OUTMODE>
__global__ __launch_bounds__(256) void agg4_kernel(const unsigned short* __restrict__ hb,
                                                   const float* __restrict__ es,
                                                   const float* __restrict__ ed,
                                                   const int* __restrict__ rowptr,
                                                   const int* __restrict__ col,
                                                   const float* __restrict__ bias,
                                                   void* __restrict__ outp,
                                                   void* __restrict__ outp2, int N) {
    __shared__ uint2 spds[4][4][66];   // [sub][head][edge] = (src, p)
    int sub  = threadIdx.x >> 6;
    int lane = threadIdx.x & 63;
    int node = blockIdx.x * 4 + sub;
    if (node >= N) return;
    int s = rowptr[node], t = rowptr[node + 1];

    float edv[4];
    #pragma unroll
    for (int h = 0; h < 4; ++h) edv[h] = ed[(size_t)node * 4 + h];

    int hh = lane >> 4;
    float den = 0.f;
    float4 acc = make_float4(0.f, 0.f, 0.f, 0.f);
    for (int base = s; base < t; base += 64) {
        int j = base + lane;
        int m = t - base; if (m > 64) m = 64;
        int sc = 0;
        float p[4] = {0.f, 0.f, 0.f, 0.f};
        if (j < t) {
            sc = col[j];
            float4 e4 = *reinterpret_cast<const float4*>(es + (size_t)sc * 4);
            p[0] = __expf(lrelu02(e4.x + edv[0]));
            p[1] = __expf(lrelu02(e4.y + edv[1]));
            p[2] = __expf(lrelu02(e4.z + edv[2]));
            p[3] = __expf(lrelu02(e4.w + edv[3]));
        }
        #pragma unroll
        for (int h = 0; h < 4; ++h)
            spds[sub][h][lane] = make_uint2((unsigned)sc, __float_as_uint(p[h]));
        #pragma unroll 4
        for (int jj = 0; jj < m; ++jj) {
            uint2 sp = spds[sub][hh][jj];
            float a = __uint_as_float(sp.y);
            den += a;
            uint2 u = *reinterpret_cast<const uint2*>(hb + (size_t)sp.x * 256 + lane * 4);
            acc.x += bflo(u.x) * a;
            acc.y += bfhi(u.x) * a;
            acc.z += bflo(u.y) * a;
            acc.w += bfhi(u.y) * a;
        }
    }
    float inv = 1.f / den;
    float4 bv = *reinterpret_cast<const float4*>(bias + lane * 4);
    float r0 = acc.x * inv + bv.x;
    float r1 = acc.y * inv + bv.y;
    float r2 = acc.z * inv + bv.z;
    float r3 = acc.w * inv + bv.w;
    if (ACT) { r0 = eluf(r0); r1 = eluf(r1); r2 = eluf(r2); r3 = eluf(r3); }
    if constexpr (OUTMODE == 0) {
        *reinterpret_cast<float4*>((float*)outp + (size_t)node * 256 + lane * 4) =
            make_float4(r0, r1, r2, r3);
    } else if constexpr (OUTMODE == 1) {
        ushort4 o;
        o.x = f2bf(r0); o.y = f2bf(r1); o.z = f2bf(r2); o.w = f2bf(r3);
        *reinterpret_cast<ushort4*>((unsigned short*)outp + (size_t)node * 256 + lane * 4) = o;
    } else {
        ushort4 oh, ol;
        oh.x = f2bf(r0); ol.x = f2bf(r0 - bf2f(oh.x));
        oh.y = f2bf(r1); ol.y = f2bf(r1 - bf2f(oh.y));
        oh.z = f2bf(r2); ol.z = f2bf(r2 - bf2f(oh.z));
        oh.w = f2bf(r3); ol.w = f2bf(r3 - bf2f(oh.w));
        size_t o = (size_t)node * 256 + lane * 4;
        *reinterpret_cast<ushort4*>((unsigned short*)outp  + o) = oh;
        *reinterpret_cast<ushort4*>((unsigned short*)outp2 + o) = ol;
    }
}

// ---------------- fused per-dst aggregation, H=1, bf16 gather, half-wave uint loads ----------------
__global__ __launch_bounds__(256) void agg1_kernel(const unsigned short* __restrict__ hb,
                                                   const float* __restrict__ es,
                                                   const float* __restrict__ ed,
                                                   const int* __restrict__ rowptr,
                                                   const int* __restrict__ col,
                                                   const float* __restrict__ bias,
                                                   float* __restrict__ out, int N) {
    __shared__ uint2 spds[4][66];
    int sub  = threadIdx.x >> 6;
    int lane = threadIdx.x & 63;
    int node = blockIdx.x * 4 + sub;
    if (node >= N) return;
    int s = rowptr[node], t = rowptr[node + 1];
    float edv = ed[node];

    int half = lane >> 5, sl = lane & 31;
    float den = 0.f, acc0 = 0.f, acc1 = 0.f;
    for (int base = s; base < t; base += 64) {
        int j = base + lane;
        int m = t - base; if (m > 64) m = 64;
        int sc = 0;
        float p0 = 0.f;
        if (j < t) {
            sc = col[j];
            p0 = __expf(lrelu02(es[sc] + edv));
        }
        spds[sub][lane] = make_uint2((unsigned)sc, __float_as_uint(p0));
        int nit = (m + 1) >> 1;
        #pragma unroll 4
        for (int it = 0; it < nit; ++it) {
            int idx = 2 * it + half;
            uint2 sp = spds[sub][idx];
            float a = __uint_as_float(sp.y);
            den += a;
            unsigned u = *reinterpret_cast<const unsigned*>(hb + (size_t)sp.x * 64 + sl * 2);
            acc0 += bflo(u) * a;
            acc1 += bfhi(u) * a;
        }
    }
    acc0 += __shfl_xor(acc0, 32, 64);
    acc1 += __shfl_xor(acc1, 32, 64);
    den  += __shfl_xor(den, 32, 64);
    if (half == 0) {
        float inv = 1.f / den;
        float2 b = *reinterpret_cast<const float2*>(bias + sl * 2);
        *reinterpret_cast<float2*>(out + (size_t)node * 64 + sl * 2) =
            make_float2(acc0 * inv + b.x, acc1 * inv + b.y);
    }
}

// ---------------- graph mean ----------------
__global__ __launch_bounds__(256) void gmean_partial(const float* __restrict__ ne,
                                                     float* __restrict__ part, int N) {
    int d = threadIdx.x & 63, sub = threadIdx.x >> 6;
    int start = blockIdx.x * 4 + sub;
    float s = 0.f;
    for (int n = start; n < N; n += gridDim.x * 4) s += ne[(size_t)n * 64 + d];
    __shared__ float ls[256];
    ls[threadIdx.x] = s;
    __syncthreads();
    if (threadIdx.x < 64) {
        float v = ls[threadIdx.x] + ls[threadIdx.x + 64] + ls[threadIdx.x + 128] + ls[threadIdx.x + 192];
        part[blockIdx.x * 64 + d] = v;
    }
}

__global__ __launch_bounds__(64) void gmean_final(const float* __restrict__ part,
                                                  float* __restrict__ gout, int nblk, float invN) {
    int d = threadIdx.x;
    float s = 0.f;
    for (int b = 0; b < nblk; ++b) s += part[b * 64 + d];
    gout[d] = s * invN;
}

extern "C" void kernel_launch(void* const* d_in, const int* in_sizes, int n_in,
                              void* d_out, int out_size, void* d_ws, size_t ws_size,
                              hipStream_t stream) {
    const float* x   = (const float*)d_in[0];
    const int*   ei  = (const int*)d_in[1];
    const float* W1  = (const float*)d_in[2];
    const float* a1s = (const float*)d_in[3];
    const float* a1d = (const float*)d_in[4];
    const float* b1  = (const float*)d_in[5];
    const float* W2  = (const float*)d_in[6];
    const float* a2s = (const float*)d_in[7];
    const float* a2d = (const float*)d_in[8];
    const float* b2  = (const float*)d_in[9];
    const float* W3  = (const float*)d_in[10];
    const float* a3s = (const float*)d_in[11];
    const float* a3d = (const float*)d_in[12];
    const float* b3  = (const float*)d_in[13];
    float* out = (float*)d_out;

    const int N = NNODES;
    const int E = in_sizes[1] / 2;  // 800000
    const int NB = (N + 255) / 256;

    // workspace carve (16B alignment maintained)
    char* w = (char*)d_ws;
    unsigned short* Hb   = (unsigned short*)w; w += (size_t)N * 256 * 2;  // h2 bf16 (agg4 gather)
    unsigned short* B0b  = (unsigned short*)w; w += (size_t)N * 256 * 2;  // agg2 out bf16 (gemm3 A)
    unsigned short* H3b  = (unsigned short*)w; w += (size_t)N * 64 * 2;   // h3 bf16 (agg1 gather)
    unsigned short* A1h  = (unsigned short*)w; w += (size_t)N * 256 * 2;  // h1' hi (gemm2 A)
    unsigned short* A1l  = (unsigned short*)w; w += (size_t)N * 256 * 2;  // h1' lo
    float* zn = (float*)w; w += (size_t)N * 64 * 4;                       // layer-1 x-space agg
    float* es = (float*)w; w += (size_t)N * 4 * 4;
    float* ed = (float*)w; w += (size_t)N * 4 * 4;
    unsigned short* W2Th = (unsigned short*)w; w += 256 * 256 * 2;
    unsigned short* W2Tl = (unsigned short*)w; w += 256 * 256 * 2;
    unsigned short* W3Th = (unsigned short*)w; w += 64 * 256 * 2;
    unsigned short* W3Tl = (unsigned short*)w; w += 64 * 256 * 2;
    float* w1s = (float*)w; w += 64 * 4;
    float* w1d = (float*)w; w += 64 * 4;
    int* deg    = (int*)w; w += (size_t)N * 4;
    int* rowptr = (int*)w; w += (size_t)(N + 2) * 4;
    int* fill   = (int*)w; w += (size_t)N * 4;
    int* col    = (int*)w; w += (size_t)(E + N) * 4;
    int* bsum   = (int*)w; w += 256 * 4;
    int* boff   = (int*)w; w += 256 * 4;
    float* part = (float*)w; w += 128 * 64 * 4;
    (void)ws_size; (void)n_in; (void)out_size;

    // ---- CSR build ----
    hipMemsetAsync(deg, 0, (size_t)N * 4, stream);
    deg_count_kernel<<<(E + 255) / 256, 256, 0, stream>>>(ei, deg, E);
    scan_partial_kernel<<<NB, 256, 0, stream>>>(deg, bsum, N);
    scan_blocks_kernel<<<1, 256, 0, stream>>>(bsum, boff, rowptr + N, NB);
    scan_final_kernel<<<NB, 256, 0, stream>>>(deg, boff, rowptr, fill, N);
    scatter_kernel<<<(E + N + 255) / 256, 256, 0, stream>>>(ei, fill, col, E, N);
    // weight prep (W2/W3 split + w1s/w1d vectors)
    wprep_kernel<<<321, 256, 0, stream>>>(W1, a1s, a1d, W2, W3,
                                          W2Th, W2Tl, W3Th, W3Tl, w1s, w1d);

    // ---- Layer 1 (x-space aggregation): es1/ed1 -> aggx -> gemm1z ----
    esed1_kernel<<<NB, 256, 0, stream>>>(x, w1s, w1d, es, ed, N);
    aggx_kernel<<<(N + 3) / 4, 256, 0, stream>>>(x, es, ed, rowptr, col, zn, N);
    gemm1z_kernel<<<dim3((N + 63) / 64, 4), 256, 0, stream>>>(zn, W1, b1, A1h, A1l, N);

    // ---- Layer 2: (A1h+A1l)[N,256] @ W2, split-bf16 MFMA; then agg4 on h2 ----
    gemm2_mfma_kernel<<<dim3((N + 127) / 128, 2), 256, 0, stream>>>(
        A1h, A1l, W2Th, W2Tl, Hb, a2s, a2d, es, ed, N);
    agg4_kernel<1, 1><<<(N + 3) / 4, 256, 0, stream>>>(Hb, es, ed, rowptr, col, b2, B0b, nullptr, N);

    // ---- Layer 3: B0b[N,256] @ W3, bf16-A MFMA; agg1 on h3 ----
    gemm3_mfma_kernel<<<(N + 127) / 128, 256, 0, stream>>>(
        B0b, W3Th, W3Tl, H3b, a3s, a3d, es, ed, N);
    agg1_kernel<<<(N + 3) / 4, 256, 0, stream>>>(H3b, es, ed, rowptr, col, b3, out, N);

    // ---- graph mean ----
    gmean_partial<<<128, 256, 0, stream>>>(out, part, N);
    gmean_final<<<1, 64, 0, stream>>>(part, out + (size_t)N * 64, 128, 1.0f / N);
}

// Round 11
// 388.712 us; speedup vs baseline: 1.2044x; 1.1024x over previous
//
#include <hip/hip_runtime.h>
#include <math.h>

#define NNODES 50000

typedef __attribute__((ext_vector_type(8))) short short8;   // 8 bf16 (4 VGPRs)
typedef __attribute__((ext_vector_type(4))) float f32x4;    // MFMA accumulator

__device__ __forceinline__ unsigned short f2bf(float f) {
    unsigned u = __float_as_uint(f);
    u += 0x7fffu + ((u >> 16) & 1);   // RTN-even
    return (unsigned short)(u >> 16);
}
__device__ __forceinline__ float bf2f(unsigned short h) {
    return __uint_as_float(((unsigned)h) << 16);
}
__device__ __forceinline__ float bflo(unsigned u) { return __uint_as_float(u << 16); }
__device__ __forceinline__ float bfhi(unsigned u) { return __uint_as_float(u & 0xffff0000u); }

// ---------------- CSR build ----------------
// deg[] zeroed via hipMemsetAsync. deg_count assigns each edge its within-dst rank;
// scatter is then atomic-free (coalesced reads + one L2-resident random read + store).
__global__ __launch_bounds__(256) void deg_count_kernel(const int* __restrict__ ei,
                                                        int* __restrict__ deg,
                                                        int* __restrict__ rank, int E) {
    int i = blockIdx.x * 256 + threadIdx.x;
    if (i < E) rank[i] = atomicAdd(&deg[ei[E + i]], 1);
}

__global__ __launch_bounds__(256) void scan_partial_kernel(const int* __restrict__ deg,
                                                           int* __restrict__ bsum, int N) {
    __shared__ int ls[256];
    int t = threadIdx.x;
    int i = blockIdx.x * 256 + t;
    ls[t] = (i < N) ? deg[i] + 1 : 0;   // +1 self-loop
    __syncthreads();
    #pragma unroll
    for (int off = 128; off; off >>= 1) {
        if (t < off) ls[t] += ls[t + off];
        __syncthreads();
    }
    if (t == 0) bsum[blockIdx.x] = ls[0];
}

__global__ __launch_bounds__(256) void scan_blocks_kernel(const int* __restrict__ bsum,
                                                          int* __restrict__ boff,
                                                          int* __restrict__ rowptrN, int nblk) {
    __shared__ int ls[256];
    int t = threadIdx.x;
    int v = (t < nblk) ? bsum[t] : 0;
    ls[t] = v;
    __syncthreads();
    for (int off = 1; off < 256; off <<= 1) {
        int u = (t >= off) ? ls[t - off] : 0;
        __syncthreads();
        ls[t] += u;
        __syncthreads();
    }
    if (t < nblk) boff[t] = ls[t] - v;
    if (t == 255) *rowptrN = ls[255];
}

__global__ __launch_bounds__(256) void scan_final_kernel(const int* __restrict__ deg,
                                                         const int* __restrict__ boff,
                                                         int* __restrict__ rowptr, int N) {
    __shared__ int ls[256];
    int t = threadIdx.x;
    int i = blockIdx.x * 256 + t;
    int v = (i < N) ? deg[i] + 1 : 0;   // +1 self-loop
    ls[t] = v;
    __syncthreads();
    for (int off = 1; off < 256; off <<= 1) {
        int u = (t >= off) ? ls[t - off] : 0;
        __syncthreads();
        ls[t] += u;
        __syncthreads();
    }
    if (i < N) rowptr[i] = boff[blockIdx.x] + ls[t] - v;
}

// atomic-free scatter: edges use precomputed rank; self-loop takes the segment's last slot.
__global__ __launch_bounds__(256) void scatter_kernel(const int* __restrict__ ei,
                                                      const int* __restrict__ rank,
                                                      const int* __restrict__ deg,
                                                      const int* __restrict__ rowptr,
                                                      int* __restrict__ col, int E, int N) {
    int i = blockIdx.x * 256 + threadIdx.x;
    int total = E + N;
    if (i >= total) return;
    if (i < E) {
        int d = ei[E + i];
        col[rowptr[d] + rank[i]] = ei[i];
    } else {
        int d = i - E;
        col[rowptr[d] + deg[d]] = d;
    }
}

// ---------------- weight prep: W2/W3 transpose+split; w1s/w1d = W1^T a1s/a1d ----------------
__global__ __launch_bounds__(256) void wprep_kernel(const float* __restrict__ W1,
                                                    const float* __restrict__ a1s,
                                                    const float* __restrict__ a1d,
                                                    const float* __restrict__ W2,
                                                    const float* __restrict__ W3,
                                                    unsigned short* __restrict__ W2Th,
                                                    unsigned short* __restrict__ W2Tl,
                                                    unsigned short* __restrict__ W3Th,
                                                    unsigned short* __restrict__ W3Tl,
                                                    float* __restrict__ w1s,
                                                    float* __restrict__ w1d) {
    int b = blockIdx.x;
    if (b < 256) {            // W2: 256x256
        int k = b, n = threadIdx.x;
        float w = W2[k * 256 + n];
        unsigned short h = f2bf(w);
        unsigned short l = f2bf(w - bf2f(h));
        W2Th[n * 256 + k] = h;
        W2Tl[n * 256 + k] = l;
    } else if (b < 320) {     // W3: 256x64 -> [64][256]
        int n = b - 256, k = threadIdx.x;
        float w = W3[k * 64 + n];
        unsigned short h = f2bf(w);
        unsigned short l = f2bf(w - bf2f(h));
        W3Th[n * 256 + k] = h;
        W3Tl[n * 256 + k] = l;
    } else {                  // w1s[h*16+k] = sum_d W1[k][h*64+d]*a1s[h*64+d]
        int t = threadIdx.x;
        if (t < 128) {
            int which = t >> 6;           // 0: w1s, 1: w1d
            int hk = t & 63;
            int h = hk >> 4, k = hk & 15;
            const float* av = which ? a1d : a1s;
            float s = 0.f;
            for (int d = 0; d < 64; ++d)
                s += W1[k * 256 + h * 64 + d] * av[h * 64 + d];
            (which ? w1d : w1s)[hk] = s;
        }
    }
}

// ---------------- layer-1 attention coefficients: es1/ed1 = x . w1s/w1d ----------------
__global__ __launch_bounds__(256) void esed1_kernel(const float* __restrict__ x,
                                                    const float* __restrict__ w1s,
                                                    const float* __restrict__ w1d,
                                                    float* __restrict__ es,
                                                    float* __restrict__ ed, int N) {
    int i = blockIdx.x * 256 + threadIdx.x;
    if (i >= N) return;
    float xv[16];
    #pragma unroll
    for (int p = 0; p < 4; ++p) {
        float4 v = *reinterpret_cast<const float4*>(x + (size_t)i * 16 + p * 4);
        xv[p * 4 + 0] = v.x; xv[p * 4 + 1] = v.y; xv[p * 4 + 2] = v.z; xv[p * 4 + 3] = v.w;
    }
    float4 se, de;
    float* sp = &se.x; float* dp = &de.x;
    #pragma unroll
    for (int h = 0; h < 4; ++h) {
        float s = 0.f, d = 0.f;
        #pragma unroll
        for (int k = 0; k < 16; ++k) {
            s += xv[k] * w1s[h * 16 + k];
            d += xv[k] * w1d[h * 16 + k];
        }
        sp[h] = s; dp[h] = d;
    }
    *reinterpret_cast<float4*>(es + (size_t)i * 4) = se;
    *reinterpret_cast<float4*>(ed + (size_t)i * 4) = de;
}

__device__ __forceinline__ float lrelu02(float x) { return x > 0.f ? x : 0.2f * x; }
__device__ __forceinline__ float eluf(float x)    { return x > 0.f ? x : expm1f(x); }

// ---------------- layer-1 x-space aggregation ----------------
__global__ __launch_bounds__(256) void aggx_kernel(const float* __restrict__ x,
                                                   const float* __restrict__ es,
                                                   const float* __restrict__ ed,
                                                   const int* __restrict__ rowptr,
                                                   const int* __restrict__ col,
                                                   float* __restrict__ zn, int N) {
    __shared__ int    slds[4][64];
    __shared__ float4 plds[4][64];
    int sub  = threadIdx.x >> 6;
    int lane = threadIdx.x & 63;
    int node = blockIdx.x * 4 + sub;
    if (node >= N) return;
    int s = rowptr[node], t = rowptr[node + 1];

    float edv[4];
    #pragma unroll
    for (int h = 0; h < 4; ++h) edv[h] = ed[(size_t)node * 4 + h];

    int eg = lane >> 4, d = lane & 15;
    float acc[4] = {0.f, 0.f, 0.f, 0.f};
    float den[4] = {0.f, 0.f, 0.f, 0.f};

    for (int base = s; base < t; base += 64) {
        int j = base + lane;
        int m = t - base; if (m > 64) m = 64;
        int sc = 0;
        float4 p = make_float4(0.f, 0.f, 0.f, 0.f);
        if (j < t) {
            sc = col[j];
            float4 e4 = *reinterpret_cast<const float4*>(es + (size_t)sc * 4);
            p.x = __expf(lrelu02(e4.x + edv[0]));
            p.y = __expf(lrelu02(e4.y + edv[1]));
            p.z = __expf(lrelu02(e4.z + edv[2]));
            p.w = __expf(lrelu02(e4.w + edv[3]));
        }
        slds[sub][lane] = sc;
        plds[sub][lane] = p;
        int nit = (m + 3) >> 2;
        #pragma unroll 4
        for (int it = 0; it < nit; ++it) {
            int e = it * 4 + eg;             // phantom edges have p=0 (all 64 slots written)
            int scj = slds[sub][e];
            float4 pj = plds[sub][e];
            float xv = x[(size_t)scj * 16 + d];
            acc[0] += pj.x * xv; acc[1] += pj.y * xv;
            acc[2] += pj.z * xv; acc[3] += pj.w * xv;
            den[0] += pj.x; den[1] += pj.y; den[2] += pj.z; den[3] += pj.w;
        }
    }
    #pragma unroll
    for (int h = 0; h < 4; ++h) {
        acc[h] += __shfl_xor(acc[h], 16, 64);
        acc[h] += __shfl_xor(acc[h], 32, 64);
        den[h] += __shfl_xor(den[h], 16, 64);
        den[h] += __shfl_xor(den[h], 32, 64);
    }
    float a = (eg == 0) ? acc[0] : (eg == 1) ? acc[1] : (eg == 2) ? acc[2] : acc[3];
    float dn = (eg == 0) ? den[0] : (eg == 1) ? den[1] : (eg == 2) ? den[2] : den[3];
    zn[(size_t)node * 64 + lane] = a / dn;
}

// ---------------- layer-1 GEMM on aggregated z: h1' = elu(zn.W1 + b1), hi/lo-split out ----------------
__global__ __launch_bounds__(256) void gemm1z_kernel(const float* __restrict__ zn,
                                                     const float* __restrict__ W1,
                                                     const float* __restrict__ b1,
                                                     unsigned short* __restrict__ A1h,
                                                     unsigned short* __restrict__ A1l,
                                                     int M) {
    __shared__ __align__(16) float As[16][64];
    __shared__ __align__(16) float Bs[16][64];
    int tid = threadIdx.x;
    int bm = blockIdx.x * 64;
    int hy = blockIdx.y;
    int tm = (tid >> 4) * 4;
    int tn = (tid & 15) * 4;
    float acc[4][4] = {};
    int ar  = tid >> 2;
    int akk = (tid & 3) * 4;
    int brr = tid >> 4;
    int bcc = (tid & 15) * 4;
    {
        int grow = bm + ar;
        float4 av = (grow < M)
            ? *reinterpret_cast<const float4*>(zn + (size_t)grow * 64 + hy * 16 + akk)
            : make_float4(0.f, 0.f, 0.f, 0.f);
        As[akk + 0][ar] = av.x;
        As[akk + 1][ar] = av.y;
        As[akk + 2][ar] = av.z;
        As[akk + 3][ar] = av.w;
        float4 bv = *reinterpret_cast<const float4*>(W1 + (size_t)brr * 256 + hy * 64 + bcc);
        *reinterpret_cast<float4*>(&Bs[brr][bcc]) = bv;
        __syncthreads();
        #pragma unroll
        for (int kk = 0; kk < 16; ++kk) {
            float4 a4 = *reinterpret_cast<const float4*>(&As[kk][tm]);
            float4 b4 = *reinterpret_cast<const float4*>(&Bs[kk][tn]);
            float a[4] = {a4.x, a4.y, a4.z, a4.w};
            float b[4] = {b4.x, b4.y, b4.z, b4.w};
            #pragma unroll
            for (int i = 0; i < 4; ++i)
                #pragma unroll
                for (int j = 0; j < 4; ++j) acc[i][j] += a[i] * b[j];
        }
    }
    float4 bb = *reinterpret_cast<const float4*>(b1 + hy * 64 + tn);
    #pragma unroll
    for (int i = 0; i < 4; ++i) {
        int gr = bm + tm + i;
        if (gr < M) {
            float r0 = eluf(acc[i][0] + bb.x);
            float r1 = eluf(acc[i][1] + bb.y);
            float r2 = eluf(acc[i][2] + bb.z);
            float r3 = eluf(acc[i][3] + bb.w);
            ushort4 oh, ol;
            oh.x = f2bf(r0); ol.x = f2bf(r0 - bf2f(oh.x));
            oh.y = f2bf(r1); ol.y = f2bf(r1 - bf2f(oh.y));
            oh.z = f2bf(r2); ol.z = f2bf(r2 - bf2f(oh.z));
            oh.w = f2bf(r3); ol.w = f2bf(r3 - bf2f(oh.w));
            size_t o = (size_t)gr * 256 + hy * 64 + tn;
            *reinterpret_cast<ushort4*>(A1h + o) = oh;
            *reinterpret_cast<ushort4*>(A1l + o) = ol;
        }
    }
}

#define LDK 40

// ---------------- layer-2 GEMM: split-bf16 MFMA, pre-split A, fused es/ed epilogue ----------------
__global__ __launch_bounds__(256) void gemm2_mfma_kernel(const unsigned short* __restrict__ Ahb,
                                                         const unsigned short* __restrict__ Alb,
                                                         const unsigned short* __restrict__ WTh,
                                                         const unsigned short* __restrict__ WTl,
                                                         unsigned short* __restrict__ Cb,
                                                         const float* __restrict__ as_,
                                                         const float* __restrict__ ad_,
                                                         float* __restrict__ es,
                                                         float* __restrict__ ed,
                                                         int M) {
    __shared__ __align__(16) unsigned short Ah[128][LDK], Al[128][LDK];
    __shared__ __align__(16) unsigned short Bh[128][LDK], Bl[128][LDK];
    int tid  = threadIdx.x;
    int lane = tid & 63, wave = tid >> 6;
    int wm = wave >> 1, wn = wave & 1;
    int bm = blockIdx.x * 128;
    int bn = blockIdx.y * 128;
    int c = lane & 15, q = lane >> 4;

    f32x4 acc[4][4] = {};

    for (int k0 = 0; k0 < 256; k0 += 32) {
        #pragma unroll
        for (int p = 0; p < 2; ++p) {
            int idx = p * 256 + tid;
            int r   = idx >> 2;
            int kc  = (idx & 3) * 8;
            int grow = bm + r;
            size_t go = (size_t)grow * 256 + k0 + kc;
            uint4 vh = make_uint4(0u,0u,0u,0u), vl = make_uint4(0u,0u,0u,0u);
            if (grow < M) {
                vh = *reinterpret_cast<const uint4*>(Ahb + go);
                vl = *reinterpret_cast<const uint4*>(Alb + go);
            }
            *reinterpret_cast<uint4*>(&Ah[r][kc]) = vh;
            *reinterpret_cast<uint4*>(&Al[r][kc]) = vl;
        }
        #pragma unroll
        for (int p = 0; p < 2; ++p) {
            int idx = p * 256 + tid;
            int n   = idx >> 2;
            int kc  = (idx & 3) * 8;
            const size_t go = (size_t)(bn + n) * 256 + k0 + kc;
            *reinterpret_cast<uint4*>(&Bh[n][kc]) = *reinterpret_cast<const uint4*>(WTh + go);
            *reinterpret_cast<uint4*>(&Bl[n][kc]) = *reinterpret_cast<const uint4*>(WTl + go);
        }
        __syncthreads();

        short8 bh[4], bl[4];
        #pragma unroll
        for (int nt = 0; nt < 4; ++nt) {
            bh[nt] = *reinterpret_cast<const short8*>(&Bh[wn * 64 + nt * 16 + c][q * 8]);
            bl[nt] = *reinterpret_cast<const short8*>(&Bl[wn * 64 + nt * 16 + c][q * 8]);
        }
        #pragma unroll
        for (int mt = 0; mt < 4; ++mt) {
            short8 ah = *reinterpret_cast<const short8*>(&Ah[wm * 64 + mt * 16 + c][q * 8]);
            short8 al = *reinterpret_cast<const short8*>(&Al[wm * 64 + mt * 16 + c][q * 8]);
            #pragma unroll
            for (int nt = 0; nt < 4; ++nt) {
                acc[mt][nt] = __builtin_amdgcn_mfma_f32_16x16x32_bf16(ah, bh[nt], acc[mt][nt], 0, 0, 0);
                acc[mt][nt] = __builtin_amdgcn_mfma_f32_16x16x32_bf16(ah, bl[nt], acc[mt][nt], 0, 0, 0);
                acc[mt][nt] = __builtin_amdgcn_mfma_f32_16x16x32_bf16(al, bh[nt], acc[mt][nt], 0, 0, 0);
            }
        }
        __syncthreads();
    }

    #pragma unroll
    for (int mt = 0; mt < 4; ++mt) {
        #pragma unroll
        for (int r = 0; r < 4; ++r) {
            int gr = bm + wm * 64 + mt * 16 + q * 4 + r;
            if (gr < M) {
                #pragma unroll
                for (int nt = 0; nt < 4; ++nt) {
                    Cb[(size_t)gr * 256 + bn + wn * 64 + nt * 16 + c] = f2bf(acc[mt][nt][r]);
                }
            }
        }
    }
    int head = blockIdx.y * 2 + wn;
    float asv[4], adv[4];
    #pragma unroll
    for (int nt = 0; nt < 4; ++nt) {
        asv[nt] = as_[head * 64 + nt * 16 + c];
        adv[nt] = ad_[head * 64 + nt * 16 + c];
    }
    #pragma unroll
    for (int mt = 0; mt < 4; ++mt) {
        #pragma unroll
        for (int r = 0; r < 4; ++r) {
            float s = 0.f, d = 0.f;
            #pragma unroll
            for (int nt = 0; nt < 4; ++nt) {
                s += acc[mt][nt][r] * asv[nt];
                d += acc[mt][nt][r] * adv[nt];
            }
            #pragma unroll
            for (int off = 1; off < 16; off <<= 1) {
                s += __shfl_xor(s, off, 64);
                d += __shfl_xor(d, off, 64);
            }
            int gr = bm + wm * 64 + mt * 16 + q * 4 + r;
            if (c == 0 && gr < M) {
                es[(size_t)gr * 4 + head] = s;
                ed[(size_t)gr * 4 + head] = d;
            }
        }
    }
}

// ---------------- layer-3 GEMM: bf16-A MFMA, W3 split hi/lo ----------------
__global__ __launch_bounds__(256) void gemm3_mfma_kernel(const unsigned short* __restrict__ Ab,
                                                         const unsigned short* __restrict__ WTh,
                                                         const unsigned short* __restrict__ WTl,
                                                         unsigned short* __restrict__ Cb,
                                                         const float* __restrict__ as_,
                                                         const float* __restrict__ ad_,
                                                         float* __restrict__ es,
                                                         float* __restrict__ ed,
                                                         int M) {
    __shared__ __align__(16) unsigned short Ah[128][LDK];
    __shared__ __align__(16) unsigned short Bh[64][LDK], Bl[64][LDK];
    int tid = threadIdx.x, lane = tid & 63, wave = tid >> 6;
    int bm = blockIdx.x * 128;
    int c = lane & 15, q = lane >> 4;
    f32x4 acc[2][4] = {};

    for (int k0 = 0; k0 < 256; k0 += 32) {
        #pragma unroll
        for (int p = 0; p < 2; ++p) {
            int idx = p * 256 + tid;
            int r   = idx >> 2;
            int kf  = (idx & 3) * 8;
            int grow = bm + r;
            uint4 v = (grow < M)
                ? *reinterpret_cast<const uint4*>(Ab + (size_t)grow * 256 + k0 + kf)
                : make_uint4(0u, 0u, 0u, 0u);
            *reinterpret_cast<uint4*>(&Ah[r][kf]) = v;
        }
        {
            int n  = tid >> 2;
            int kc = (tid & 3) * 8;
            size_t go = (size_t)n * 256 + k0 + kc;
            *reinterpret_cast<uint4*>(&Bh[n][kc]) = *reinterpret_cast<const uint4*>(WTh + go);
            *reinterpret_cast<uint4*>(&Bl[n][kc]) = *reinterpret_cast<const uint4*>(WTl + go);
        }
        __syncthreads();

        short8 bh[4], bl[4];
        #pragma unroll
        for (int nt = 0; nt < 4; ++nt) {
            bh[nt] = *reinterpret_cast<const short8*>(&Bh[nt * 16 + c][q * 8]);
            bl[nt] = *reinterpret_cast<const short8*>(&Bl[nt * 16 + c][q * 8]);
        }
        #pragma unroll
        for (int mt = 0; mt < 2; ++mt) {
            short8 a = *reinterpret_cast<const short8*>(&Ah[wave * 32 + mt * 16 + c][q * 8]);
            #pragma unroll
            for (int nt = 0; nt < 4; ++nt) {
                acc[mt][nt] = __builtin_amdgcn_mfma_f32_16x16x32_bf16(a, bh[nt], acc[mt][nt], 0, 0, 0);
                acc[mt][nt] = __builtin_amdgcn_mfma_f32_16x16x32_bf16(a, bl[nt], acc[mt][nt], 0, 0, 0);
            }
        }
        __syncthreads();
    }

    float asv[4], adv[4];
    #pragma unroll
    for (int nt = 0; nt < 4; ++nt) { asv[nt] = as_[nt * 16 + c]; adv[nt] = ad_[nt * 16 + c]; }
    #pragma unroll
    for (int mt = 0; mt < 2; ++mt) {
        #pragma unroll
        for (int r = 0; r < 4; ++r) {
            int gr = bm + wave * 32 + mt * 16 + q * 4 + r;
            bool ok = gr < M;
            if (ok) {
                #pragma unroll
                for (int nt = 0; nt < 4; ++nt)
                    Cb[(size_t)gr * 64 + nt * 16 + c] = f2bf(acc[mt][nt][r]);
            }
            float s = 0.f, d = 0.f;
            #pragma unroll
            for (int nt = 0; nt < 4; ++nt) {
                s += acc[mt][nt][r] * asv[nt];
                d += acc[mt][nt][r] * adv[nt];
            }
            #pragma unroll
            for (int off = 1; off < 16; off <<= 1) {
                s += __shfl_xor(s, off, 64);
                d += __shfl_xor(d, off, 64);
            }
            if (c == 0 && ok) { es[gr] = s; ed[gr] = d; }
        }
    }
}

// ---------------- fused per-dst aggregation, H=4, bf16 gather, single-pass softmax ----------------
template <int ACT, int OUTMODE>
__global__ __launch_bounds__(256) void agg4_kernel(const unsigned short* __restrict__ hb,
                                                   const float* __restrict__ es,
                                                   const float* __restrict__ ed,
                                                   const int* __restrict__ rowptr,
                                                   const int* __restrict__ col,
                                                   const float* __restrict__ bias,
                                                   void* __restrict__ outp,
                                                   void* __restrict__ outp2, int N) {
    __shared__ uint2 spds[4][4][66];   // [sub][head][edge] = (src, p)
    int sub  = threadIdx.x >> 6;
    int lane = threadIdx.x & 63;
    int node = blockIdx.x * 4 + sub;
    if (node >= N) return;
    int s = rowptr[node], t = rowptr[node + 1];

    float edv[4];
    #pragma unroll
    for (int h = 0; h < 4; ++h) edv[h] = ed[(size_t)node * 4 + h];

    int hh = lane >> 4;
    float den = 0.f;
    float4 acc = make_float4(0.f, 0.f, 0.f, 0.f);
    for (int base = s; base < t; base += 64) {
        int j = base + lane;
        int m = t - base; if (m > 64) m = 64;
        int sc = 0;
        float p[4] = {0.f, 0.f, 0.f, 0.f};
        if (j < t) {
            sc = col[j];
            float4 e4 = *reinterpret_cast<const float4*>(es + (size_t)sc * 4);
            p[0] = __expf(lrelu02(e4.x + edv[0]));
            p[1] = __expf(lrelu02(e4.y + edv[1]));
            p[2] = __expf(lrelu02(e4.z + edv[2]));
            p[3] = __expf(lrelu02(e4.w + edv[3]));
        }
        #pragma unroll
        for (int h = 0; h < 4; ++h)
            spds[sub][h][lane] = make_uint2((unsigned)sc, __float_as_uint(p[h]));
        #pragma unroll 4
        for (int jj = 0; jj < m; ++jj) {
            uint2 sp = spds[sub][hh][jj];
            float a = __uint_as_float(sp.y);
            den += a;
            uint2 u = *reinterpret_cast<const uint2*>(hb + (size_t)sp.x * 256 + lane * 4);
            acc.x += bflo(u.x) * a;
            acc.y += bfhi(u.x) * a;
            acc.z += bflo(u.y) * a;
            acc.w += bfhi(u.y) * a;
        }
    }
    float inv = 1.f / den;
    float4 bv = *reinterpret_cast<const float4*>(bias + lane * 4);
    float r0 = acc.x * inv + bv.x;
    float r1 = acc.y * inv + bv.y;
    float r2 = acc.z * inv + bv.z;
    float r3 = acc.w * inv + bv.w;
    if (ACT) { r0 = eluf(r0); r1 = eluf(r1); r2 = eluf(r2); r3 = eluf(r3); }
    if constexpr (OUTMODE == 0) {
        *reinterpret_cast<float4*>((float*)outp + (size_t)node * 256 + lane * 4) =
            make_float4(r0, r1, r2, r3);
    } else if constexpr (OUTMODE == 1) {
        ushort4 o;
        o.x = f2bf(r0); o.y = f2bf(r1); o.z = f2bf(r2); o.w = f2bf(r3);
        *reinterpret_cast<ushort4*>((unsigned short*)outp + (size_t)node * 256 + lane * 4) = o;
    } else {
        ushort4 oh, ol;
        oh.x = f2bf(r0); ol.x = f2bf(r0 - bf2f(oh.x));
        oh.y = f2bf(r1); ol.y = f2bf(r1 - bf2f(oh.y));
        oh.z = f2bf(r2); ol.z = f2bf(r2 - bf2f(oh.z));
        oh.w = f2bf(r3); ol.w = f2bf(r3 - bf2f(oh.w));
        size_t o = (size_t)node * 256 + lane * 4;
        *reinterpret_cast<ushort4*>((unsigned short*)outp  + o) = oh;
        *reinterpret_cast<ushort4*>((unsigned short*)outp2 + o) = ol;
    }
}

// ---------------- fused per-dst aggregation, H=1, bf16 gather, half-wave uint loads ----------------
__global__ __launch_bounds__(256) void agg1_kernel(const unsigned short* __restrict__ hb,
                                                   const float* __restrict__ es,
                                                   const float* __restrict__ ed,
                                                   const int* __restrict__ rowptr,
                                                   const int* __restrict__ col,
                                                   const float* __restrict__ bias,
                                                   float* __restrict__ out, int N) {
    __shared__ uint2 spds[4][66];
    int sub  = threadIdx.x >> 6;
    int lane = threadIdx.x & 63;
    int node = blockIdx.x * 4 + sub;
    if (node >= N) return;
    int s = rowptr[node], t = rowptr[node + 1];
    float edv = ed[node];

    int half = lane >> 5, sl = lane & 31;
    float den = 0.f, acc0 = 0.f, acc1 = 0.f;
    for (int base = s; base < t; base += 64) {
        int j = base + lane;
        int m = t - base; if (m > 64) m = 64;
        int sc = 0;
        float p0 = 0.f;
        if (j < t) {
            sc = col[j];
            p0 = __expf(lrelu02(es[sc] + edv));
        }
        spds[sub][lane] = make_uint2((unsigned)sc, __float_as_uint(p0));
        int nit = (m + 1) >> 1;
        #pragma unroll 4
        for (int it = 0; it < nit; ++it) {
            int idx = 2 * it + half;
            uint2 sp = spds[sub][idx];
            float a = __uint_as_float(sp.y);
            den += a;
            unsigned u = *reinterpret_cast<const unsigned*>(hb + (size_t)sp.x * 64 + sl * 2);
            acc0 += bflo(u) * a;
            acc1 += bfhi(u) * a;
        }
    }
    acc0 += __shfl_xor(acc0, 32, 64);
    acc1 += __shfl_xor(acc1, 32, 64);
    den  += __shfl_xor(den, 32, 64);
    if (half == 0) {
        float inv = 1.f / den;
        float2 b = *reinterpret_cast<const float2*>(bias + sl * 2);
        *reinterpret_cast<float2*>(out + (size_t)node * 64 + sl * 2) =
            make_float2(acc0 * inv + b.x, acc1 * inv + b.y);
    }
}

// ---------------- graph mean ----------------
__global__ __launch_bounds__(256) void gmean_partial(const float* __restrict__ ne,
                                                     float* __restrict__ part, int N) {
    int d = threadIdx.x & 63, sub = threadIdx.x >> 6;
    int start = blockIdx.x * 4 + sub;
    float s = 0.f;
    for (int n = start; n < N; n += gridDim.x * 4) s += ne[(size_t)n * 64 + d];
    __shared__ float ls[256];
    ls[threadIdx.x] = s;
    __syncthreads();
    if (threadIdx.x < 64) {
        float v = ls[threadIdx.x] + ls[threadIdx.x + 64] + ls[threadIdx.x + 128] + ls[threadIdx.x + 192];
        part[blockIdx.x * 64 + d] = v;
    }
}

__global__ __launch_bounds__(64) void gmean_final(const float* __restrict__ part,
                                                  float* __restrict__ gout, int nblk, float invN) {
    int d = threadIdx.x;
    float s = 0.f;
    for (int b = 0; b < nblk; ++b) s += part[b * 64 + d];
    gout[d] = s * invN;
}

extern "C" void kernel_launch(void* const* d_in, const int* in_sizes, int n_in,
                              void* d_out, int out_size, void* d_ws, size_t ws_size,
                              hipStream_t stream) {
    const float* x   = (const float*)d_in[0];
    const int*   ei  = (const int*)d_in[1];
    const float* W1  = (const float*)d_in[2];
    const float* a1s = (const float*)d_in[3];
    const float* a1d = (const float*)d_in[4];
    const float* b1  = (const float*)d_in[5];
    const float* W2  = (const float*)d_in[6];
    const float* a2s = (const float*)d_in[7];
    const float* a2d = (const float*)d_in[8];
    const float* b2  = (const float*)d_in[9];
    const float* W3  = (const float*)d_in[10];
    const float* a3s = (const float*)d_in[11];
    const float* a3d = (const float*)d_in[12];
    const float* b3  = (const float*)d_in[13];
    float* out = (float*)d_out;

    const int N = NNODES;
    const int E = in_sizes[1] / 2;  // 800000
    const int NB = (N + 255) / 256;

    // workspace carve (16B alignment maintained)
    char* w = (char*)d_ws;
    unsigned short* Hb   = (unsigned short*)w; w += (size_t)N * 256 * 2;  // h2 bf16 (agg4 gather)
    unsigned short* B0b  = (unsigned short*)w; w += (size_t)N * 256 * 2;  // agg2 out bf16 (gemm3 A)
    unsigned short* H3b  = (unsigned short*)w; w += (size_t)N * 64 * 2;   // h3 bf16 (agg1 gather)
    unsigned short* A1h  = (unsigned short*)w; w += (size_t)N * 256 * 2;  // h1' hi (gemm2 A)
    unsigned short* A1l  = (unsigned short*)w; w += (size_t)N * 256 * 2;  // h1' lo
    float* zn = (float*)w; w += (size_t)N * 64 * 4;                       // layer-1 x-space agg
    float* es = (float*)w; w += (size_t)N * 4 * 4;
    float* ed = (float*)w; w += (size_t)N * 4 * 4;
    unsigned short* W2Th = (unsigned short*)w; w += 256 * 256 * 2;
    unsigned short* W2Tl = (unsigned short*)w; w += 256 * 256 * 2;
    unsigned short* W3Th = (unsigned short*)w; w += 64 * 256 * 2;
    unsigned short* W3Tl = (unsigned short*)w; w += 64 * 256 * 2;
    float* w1s = (float*)w; w += 64 * 4;
    float* w1d = (float*)w; w += 64 * 4;
    int* deg    = (int*)w; w += (size_t)N * 4;
    int* rowptr = (int*)w; w += (size_t)(N + 2) * 4;
    int* rank   = (int*)w; w += (size_t)E * 4;
    int* col    = (int*)w; w += (size_t)(E + N) * 4;
    int* bsum   = (int*)w; w += 256 * 4;
    int* boff   = (int*)w; w += 256 * 4;
    float* part = (float*)w; w += 128 * 64 * 4;
    (void)ws_size; (void)n_in; (void)out_size;

    // ---- CSR build (rank-based, atomic-free scatter) ----
    hipMemsetAsync(deg, 0, (size_t)N * 4, stream);
    deg_count_kernel<<<(E + 255) / 256, 256, 0, stream>>>(ei, deg, rank, E);
    scan_partial_kernel<<<NB, 256, 0, stream>>>(deg, bsum, N);
    scan_blocks_kernel<<<1, 256, 0, stream>>>(bsum, boff, rowptr + N, NB);
    scan_final_kernel<<<NB, 256, 0, stream>>>(deg, boff, rowptr, N);
    scatter_kernel<<<(E + N + 255) / 256, 256, 0, stream>>>(ei, rank, deg, rowptr, col, E, N);
    // weight prep (W2/W3 split + w1s/w1d vectors)
    wprep_kernel<<<321, 256, 0, stream>>>(W1, a1s, a1d, W2, W3,
                                          W2Th, W2Tl, W3Th, W3Tl, w1s, w1d);

    // ---- Layer 1 (x-space aggregation): es1/ed1 -> aggx -> gemm1z ----
    esed1_kernel<<<NB, 256, 0, stream>>>(x, w1s, w1d, es, ed, N);
    aggx_kernel<<<(N + 3) / 4, 256, 0, stream>>>(x, es, ed, rowptr, col, zn, N);
    gemm1z_kernel<<<dim3((N + 63) / 64, 4), 256, 0, stream>>>(zn, W1, b1, A1h, A1l, N);

    // ---- Layer 2: (A1h+A1l)[N,256] @ W2, split-bf16 MFMA; then agg4 on h2 ----
    gemm2_mfma_kernel<<<dim3((N + 127) / 128, 2), 256, 0, stream>>>(
        A1h, A1l, W2Th, W2Tl, Hb, a2s, a2d, es, ed, N);
    agg4_kernel<1, 1><<<(N + 3) / 4, 256, 0, stream>>>(Hb, es, ed, rowptr, col, b2, B0b, nullptr, N);

    // ---- Layer 3: B0b[N,256] @ W3, bf16-A MFMA; agg1 on h3 ----
    gemm3_mfma_kernel<<<(N + 127) / 128, 256, 0, stream>>>(
        B0b, W3Th, W3Tl, H3b, a3s, a3d, es, ed, N);
    agg1_kernel<<<(N + 3) / 4, 256, 0, stream>>>(H3b, es, ed, rowptr, col, b3, out, N);

    // ---- graph mean ----
    gmean_partial<<<128, 256, 0, stream>>>(out, part, N);
    gmean_final<<<1, 64, 0, stream>>>(part, out + (size_t)N * 64, 128, 1.0f / N);
}

// Round 12
// 382.901 us; speedup vs baseline: 1.2227x; 1.0152x over previous
//
#include <hip/hip_runtime.h>
#include <math.h>

#define NNODES 50000

typedef __attribute__((ext_vector_type(8))) short short8;   // 8 bf16 (4 VGPRs)
typedef __attribute__((ext_vector_type(4))) float f32x4;    // MFMA accumulator

__device__ __forceinline__ unsigned short f2bf(float f) {
    unsigned u = __float_as_uint(f);
    u += 0x7fffu + ((u >> 16) & 1);   // RTN-even
    return (unsigned short)(u >> 16);
}
__device__ __forceinline__ float bf2f(unsigned short h) {
    return __uint_as_float(((unsigned)h) << 16);
}
__device__ __forceinline__ float bflo(unsigned u) { return __uint_as_float(u << 16); }
__device__ __forceinline__ float bfhi(unsigned u) { return __uint_as_float(u & 0xffff0000u); }

// ---------------- CSR build ----------------
__global__ __launch_bounds__(256) void deg_count_kernel(const int* __restrict__ ei,
                                                        int* __restrict__ deg,
                                                        int* __restrict__ rank, int E) {
    int i = blockIdx.x * 256 + threadIdx.x;
    if (i < E) rank[i] = atomicAdd(&deg[ei[E + i]], 1);
}

__global__ __launch_bounds__(256) void scan_partial_kernel(const int* __restrict__ deg,
                                                           int* __restrict__ bsum, int N) {
    __shared__ int ls[256];
    int t = threadIdx.x;
    int i = blockIdx.x * 256 + t;
    ls[t] = (i < N) ? deg[i] + 1 : 0;   // +1 self-loop
    __syncthreads();
    #pragma unroll
    for (int off = 128; off; off >>= 1) {
        if (t < off) ls[t] += ls[t + off];
        __syncthreads();
    }
    if (t == 0) bsum[blockIdx.x] = ls[0];
}

__global__ __launch_bounds__(256) void scan_blocks_kernel(const int* __restrict__ bsum,
                                                          int* __restrict__ boff,
                                                          int* __restrict__ rowptrN, int nblk) {
    __shared__ int ls[256];
    int t = threadIdx.x;
    int v = (t < nblk) ? bsum[t] : 0;
    ls[t] = v;
    __syncthreads();
    for (int off = 1; off < 256; off <<= 1) {
        int u = (t >= off) ? ls[t - off] : 0;
        __syncthreads();
        ls[t] += u;
        __syncthreads();
    }
    if (t < nblk) boff[t] = ls[t] - v;
    if (t == 255) *rowptrN = ls[255];
}

__global__ __launch_bounds__(256) void scan_final_kernel(const int* __restrict__ deg,
                                                         const int* __restrict__ boff,
                                                         int* __restrict__ rowptr, int N) {
    __shared__ int ls[256];
    int t = threadIdx.x;
    int i = blockIdx.x * 256 + t;
    int v = (i < N) ? deg[i] + 1 : 0;   // +1 self-loop
    ls[t] = v;
    __syncthreads();
    for (int off = 1; off < 256; off <<= 1) {
        int u = (t >= off) ? ls[t - off] : 0;
        __syncthreads();
        ls[t] += u;
        __syncthreads();
    }
    if (i < N) rowptr[i] = boff[blockIdx.x] + ls[t] - v;
}

__global__ __launch_bounds__(256) void scatter_kernel(const int* __restrict__ ei,
                                                      const int* __restrict__ rank,
                                                      const int* __restrict__ deg,
                                                      const int* __restrict__ rowptr,
                                                      int* __restrict__ col, int E, int N) {
    int i = blockIdx.x * 256 + threadIdx.x;
    int total = E + N;
    if (i >= total) return;
    if (i < E) {
        int d = ei[E + i];
        col[rowptr[d] + rank[i]] = ei[i];
    } else {
        int d = i - E;
        col[rowptr[d] + deg[d]] = d;
    }
}

// ---------------- weight prep: W2/W3 transpose+split; w1s/w1d = W1^T a1s/a1d ----------------
__global__ __launch_bounds__(256) void wprep_kernel(const float* __restrict__ W1,
                                                    const float* __restrict__ a1s,
                                                    const float* __restrict__ a1d,
                                                    const float* __restrict__ W2,
                                                    const float* __restrict__ W3,
                                                    unsigned short* __restrict__ W2Th,
                                                    unsigned short* __restrict__ W2Tl,
                                                    unsigned short* __restrict__ W3Th,
                                                    unsigned short* __restrict__ W3Tl,
                                                    float* __restrict__ w1s,
                                                    float* __restrict__ w1d) {
    int b = blockIdx.x;
    if (b < 256) {            // W2: 256x256
        int k = b, n = threadIdx.x;
        float w = W2[k * 256 + n];
        unsigned short h = f2bf(w);
        unsigned short l = f2bf(w - bf2f(h));
        W2Th[n * 256 + k] = h;
        W2Tl[n * 256 + k] = l;
    } else if (b < 320) {     // W3: 256x64 -> [64][256]
        int n = b - 256, k = threadIdx.x;
        float w = W3[k * 64 + n];
        unsigned short h = f2bf(w);
        unsigned short l = f2bf(w - bf2f(h));
        W3Th[n * 256 + k] = h;
        W3Tl[n * 256 + k] = l;
    } else {                  // w1s[h*16+k] = sum_d W1[k][h*64+d]*a1s[h*64+d]
        int t = threadIdx.x;
        if (t < 128) {
            int which = t >> 6;
            int hk = t & 63;
            int h = hk >> 4, k = hk & 15;
            const float* av = which ? a1d : a1s;
            float s = 0.f;
            for (int d = 0; d < 64; ++d)
                s += W1[k * 256 + h * 64 + d] * av[h * 64 + d];
            (which ? w1d : w1s)[hk] = s;
        }
    }
}

// ---------------- layer-1 attention coefficients: es1/ed1 = x . w1s/w1d ----------------
__global__ __launch_bounds__(256) void esed1_kernel(const float* __restrict__ x,
                                                    const float* __restrict__ w1s,
                                                    const float* __restrict__ w1d,
                                                    float* __restrict__ es,
                                                    float* __restrict__ ed, int N) {
    int i = blockIdx.x * 256 + threadIdx.x;
    if (i >= N) return;
    float xv[16];
    #pragma unroll
    for (int p = 0; p < 4; ++p) {
        float4 v = *reinterpret_cast<const float4*>(x + (size_t)i * 16 + p * 4);
        xv[p * 4 + 0] = v.x; xv[p * 4 + 1] = v.y; xv[p * 4 + 2] = v.z; xv[p * 4 + 3] = v.w;
    }
    float4 se, de;
    float* sp = &se.x; float* dp = &de.x;
    #pragma unroll
    for (int h = 0; h < 4; ++h) {
        float s = 0.f, d = 0.f;
        #pragma unroll
        for (int k = 0; k < 16; ++k) {
            s += xv[k] * w1s[h * 16 + k];
            d += xv[k] * w1d[h * 16 + k];
        }
        sp[h] = s; dp[h] = d;
    }
    *reinterpret_cast<float4*>(es + (size_t)i * 4) = se;
    *reinterpret_cast<float4*>(ed + (size_t)i * 4) = de;
}

__device__ __forceinline__ float lrelu02(float x) { return x > 0.f ? x : 0.2f * x; }
__device__ __forceinline__ float eluf(float x)    { return x > 0.f ? x : expm1f(x); }

// ---------------- layer-1 x-space aggregation ----------------
__global__ __launch_bounds__(256) void aggx_kernel(const float* __restrict__ x,
                                                   const float* __restrict__ es,
                                                   const float* __restrict__ ed,
                                                   const int* __restrict__ rowptr,
                                                   const int* __restrict__ col,
                                                   float* __restrict__ zn, int N) {
    __shared__ int    slds[4][64];
    __shared__ float4 plds[4][64];
    int sub  = threadIdx.x >> 6;
    int lane = threadIdx.x & 63;
    int node = blockIdx.x * 4 + sub;
    if (node >= N) return;
    int s = rowptr[node], t = rowptr[node + 1];

    float edv[4];
    #pragma unroll
    for (int h = 0; h < 4; ++h) edv[h] = ed[(size_t)node * 4 + h];

    int eg = lane >> 4, d = lane & 15;
    float acc[4] = {0.f, 0.f, 0.f, 0.f};
    float den[4] = {0.f, 0.f, 0.f, 0.f};

    for (int base = s; base < t; base += 64) {
        int j = base + lane;
        int m = t - base; if (m > 64) m = 64;
        int sc = 0;
        float4 p = make_float4(0.f, 0.f, 0.f, 0.f);
        if (j < t) {
            sc = col[j];
            float4 e4 = *reinterpret_cast<const float4*>(es + (size_t)sc * 4);
            p.x = __expf(lrelu02(e4.x + edv[0]));
            p.y = __expf(lrelu02(e4.y + edv[1]));
            p.z = __expf(lrelu02(e4.z + edv[2]));
            p.w = __expf(lrelu02(e4.w + edv[3]));
        }
        slds[sub][lane] = sc;
        plds[sub][lane] = p;
        int nit = (m + 3) >> 2;
        #pragma unroll 4
        for (int it = 0; it < nit; ++it) {
            int e = it * 4 + eg;
            int scj = slds[sub][e];
            float4 pj = plds[sub][e];
            float xv = x[(size_t)scj * 16 + d];
            acc[0] += pj.x * xv; acc[1] += pj.y * xv;
            acc[2] += pj.z * xv; acc[3] += pj.w * xv;
            den[0] += pj.x; den[1] += pj.y; den[2] += pj.z; den[3] += pj.w;
        }
    }
    #pragma unroll
    for (int h = 0; h < 4; ++h) {
        acc[h] += __shfl_xor(acc[h], 16, 64);
        acc[h] += __shfl_xor(acc[h], 32, 64);
        den[h] += __shfl_xor(den[h], 16, 64);
        den[h] += __shfl_xor(den[h], 32, 64);
    }
    float a = (eg == 0) ? acc[0] : (eg == 1) ? acc[1] : (eg == 2) ? acc[2] : acc[3];
    float dn = (eg == 0) ? den[0] : (eg == 1) ? den[1] : (eg == 2) ? den[2] : den[3];
    zn[(size_t)node * 64 + lane] = a / dn;
}

// ---------------- layer-1 GEMM on aggregated z: h1' = elu(zn.W1 + b1), bf16 out ----------------
__global__ __launch_bounds__(256) void gemm1z_kernel(const float* __restrict__ zn,
                                                     const float* __restrict__ W1,
                                                     const float* __restrict__ b1,
                                                     unsigned short* __restrict__ A1h,
                                                     int M) {
    __shared__ __align__(16) float As[16][64];
    __shared__ __align__(16) float Bs[16][64];
    int tid = threadIdx.x;
    int bm = blockIdx.x * 64;
    int hy = blockIdx.y;
    int tm = (tid >> 4) * 4;
    int tn = (tid & 15) * 4;
    float acc[4][4] = {};
    int ar  = tid >> 2;
    int akk = (tid & 3) * 4;
    int brr = tid >> 4;
    int bcc = (tid & 15) * 4;
    {
        int grow = bm + ar;
        float4 av = (grow < M)
            ? *reinterpret_cast<const float4*>(zn + (size_t)grow * 64 + hy * 16 + akk)
            : make_float4(0.f, 0.f, 0.f, 0.f);
        As[akk + 0][ar] = av.x;
        As[akk + 1][ar] = av.y;
        As[akk + 2][ar] = av.z;
        As[akk + 3][ar] = av.w;
        float4 bv = *reinterpret_cast<const float4*>(W1 + (size_t)brr * 256 + hy * 64 + bcc);
        *reinterpret_cast<float4*>(&Bs[brr][bcc]) = bv;
        __syncthreads();
        #pragma unroll
        for (int kk = 0; kk < 16; ++kk) {
            float4 a4 = *reinterpret_cast<const float4*>(&As[kk][tm]);
            float4 b4 = *reinterpret_cast<const float4*>(&Bs[kk][tn]);
            float a[4] = {a4.x, a4.y, a4.z, a4.w};
            float b[4] = {b4.x, b4.y, b4.z, b4.w};
            #pragma unroll
            for (int i = 0; i < 4; ++i)
                #pragma unroll
                for (int j = 0; j < 4; ++j) acc[i][j] += a[i] * b[j];
        }
    }
    float4 bb = *reinterpret_cast<const float4*>(b1 + hy * 64 + tn);
    #pragma unroll
    for (int i = 0; i < 4; ++i) {
        int gr = bm + tm + i;
        if (gr < M) {
            ushort4 o;
            o.x = f2bf(eluf(acc[i][0] + bb.x));
            o.y = f2bf(eluf(acc[i][1] + bb.y));
            o.z = f2bf(eluf(acc[i][2] + bb.z));
            o.w = f2bf(eluf(acc[i][3] + bb.w));
            *reinterpret_cast<ushort4*>(A1h + (size_t)gr * 256 + hy * 64 + tn) = o;
        }
    }
}

#define LDK 40

// ---------------- layer-2 GEMM: bf16-A MFMA, W2 split hi/lo, fused es/ed epilogue ----------------
// A = h1' bf16 [M,256]; error from bf16 A ~2e-3 on h2 (below the bf16 rounding h2 gets anyway).
__global__ __launch_bounds__(256) void gemm2_mfma_kernel(const unsigned short* __restrict__ Ab,
                                                         const unsigned short* __restrict__ WTh,
                                                         const unsigned short* __restrict__ WTl,
                                                         unsigned short* __restrict__ Cb,
                                                         const float* __restrict__ as_,
                                                         const float* __restrict__ ad_,
                                                         float* __restrict__ es,
                                                         float* __restrict__ ed,
                                                         int M) {
    __shared__ __align__(16) unsigned short Ah[128][LDK];
    __shared__ __align__(16) unsigned short Bh[128][LDK], Bl[128][LDK];
    int tid  = threadIdx.x;
    int lane = tid & 63, wave = tid >> 6;
    int wm = wave >> 1, wn = wave & 1;
    int bm = blockIdx.x * 128;
    int bn = blockIdx.y * 128;
    int c = lane & 15, q = lane >> 4;

    f32x4 acc[4][4] = {};

    for (int k0 = 0; k0 < 256; k0 += 32) {
        #pragma unroll
        for (int p = 0; p < 2; ++p) {
            int idx = p * 256 + tid;
            int r   = idx >> 2;
            int kc  = (idx & 3) * 8;
            int grow = bm + r;
            uint4 v = (grow < M)
                ? *reinterpret_cast<const uint4*>(Ab + (size_t)grow * 256 + k0 + kc)
                : make_uint4(0u, 0u, 0u, 0u);
            *reinterpret_cast<uint4*>(&Ah[r][kc]) = v;
        }
        #pragma unroll
        for (int p = 0; p < 2; ++p) {
            int idx = p * 256 + tid;
            int n   = idx >> 2;
            int kc  = (idx & 3) * 8;
            const size_t go = (size_t)(bn + n) * 256 + k0 + kc;
            *reinterpret_cast<uint4*>(&Bh[n][kc]) = *reinterpret_cast<const uint4*>(WTh + go);
            *reinterpret_cast<uint4*>(&Bl[n][kc]) = *reinterpret_cast<const uint4*>(WTl + go);
        }
        __syncthreads();

        short8 bh[4], bl[4];
        #pragma unroll
        for (int nt = 0; nt < 4; ++nt) {
            bh[nt] = *reinterpret_cast<const short8*>(&Bh[wn * 64 + nt * 16 + c][q * 8]);
            bl[nt] = *reinterpret_cast<const short8*>(&Bl[wn * 64 + nt * 16 + c][q * 8]);
        }
        #pragma unroll
        for (int mt = 0; mt < 4; ++mt) {
            short8 ah = *reinterpret_cast<const short8*>(&Ah[wm * 64 + mt * 16 + c][q * 8]);
            #pragma unroll
            for (int nt = 0; nt < 4; ++nt) {
                acc[mt][nt] = __builtin_amdgcn_mfma_f32_16x16x32_bf16(ah, bh[nt], acc[mt][nt], 0, 0, 0);
                acc[mt][nt] = __builtin_amdgcn_mfma_f32_16x16x32_bf16(ah, bl[nt], acc[mt][nt], 0, 0, 0);
            }
        }
        __syncthreads();
    }

    #pragma unroll
    for (int mt = 0; mt < 4; ++mt) {
        #pragma unroll
        for (int r = 0; r < 4; ++r) {
            int gr = bm + wm * 64 + mt * 16 + q * 4 + r;
            if (gr < M) {
                #pragma unroll
                for (int nt = 0; nt < 4; ++nt) {
                    Cb[(size_t)gr * 256 + bn + wn * 64 + nt * 16 + c] = f2bf(acc[mt][nt][r]);
                }
            }
        }
    }
    int head = blockIdx.y * 2 + wn;
    float asv[4], adv[4];
    #pragma unroll
    for (int nt = 0; nt < 4; ++nt) {
        asv[nt] = as_[head * 64 + nt * 16 + c];
        adv[nt] = ad_[head * 64 + nt * 16 + c];
    }
    #pragma unroll
    for (int mt = 0; mt < 4; ++mt) {
        #pragma unroll
        for (int r = 0; r < 4; ++r) {
            float s = 0.f, d = 0.f;
            #pragma unroll
            for (int nt = 0; nt < 4; ++nt) {
                s += acc[mt][nt][r] * asv[nt];
                d += acc[mt][nt][r] * adv[nt];
            }
            #pragma unroll
            for (int off = 1; off < 16; off <<= 1) {
                s += __shfl_xor(s, off, 64);
                d += __shfl_xor(d, off, 64);
            }
            int gr = bm + wm * 64 + mt * 16 + q * 4 + r;
            if (c == 0 && gr < M) {
                es[(size_t)gr * 4 + head] = s;
                ed[(size_t)gr * 4 + head] = d;
            }
        }
    }
}

// ---------------- layer-3 GEMM: bf16-A MFMA, W3 split hi/lo ----------------
__global__ __launch_bounds__(256) void gemm3_mfma_kernel(const unsigned short* __restrict__ Ab,
                                                         const unsigned short* __restrict__ WTh,
                                                         const unsigned short* __restrict__ WTl,
                                                         unsigned short* __restrict__ Cb,
                                                         const float* __restrict__ as_,
                                                         const float* __restrict__ ad_,
                                                         float* __restrict__ es,
                                                         float* __restrict__ ed,
                                                         int M) {
    __shared__ __align__(16) unsigned short Ah[128][LDK];
    __shared__ __align__(16) unsigned short Bh[64][LDK], Bl[64][LDK];
    int tid = threadIdx.x, lane = tid & 63, wave = tid >> 6;
    int bm = blockIdx.x * 128;
    int c = lane & 15, q = lane >> 4;
    f32x4 acc[2][4] = {};

    for (int k0 = 0; k0 < 256; k0 += 32) {
        #pragma unroll
        for (int p = 0; p < 2; ++p) {
            int idx = p * 256 + tid;
            int r   = idx >> 2;
            int kf  = (idx & 3) * 8;
            int grow = bm + r;
            uint4 v = (grow < M)
                ? *reinterpret_cast<const uint4*>(Ab + (size_t)grow * 256 + k0 + kf)
                : make_uint4(0u, 0u, 0u, 0u);
            *reinterpret_cast<uint4*>(&Ah[r][kf]) = v;
        }
        {
            int n  = tid >> 2;
            int kc = (tid & 3) * 8;
            size_t go = (size_t)n * 256 + k0 + kc;
            *reinterpret_cast<uint4*>(&Bh[n][kc]) = *reinterpret_cast<const uint4*>(WTh + go);
            *reinterpret_cast<uint4*>(&Bl[n][kc]) = *reinterpret_cast<const uint4*>(WTl + go);
        }
        __syncthreads();

        short8 bh[4], bl[4];
        #pragma unroll
        for (int nt = 0; nt < 4; ++nt) {
            bh[nt] = *reinterpret_cast<const short8*>(&Bh[nt * 16 + c][q * 8]);
            bl[nt] = *reinterpret_cast<const short8*>(&Bl[nt * 16 + c][q * 8]);
        }
        #pragma unroll
        for (int mt = 0; mt < 2; ++mt) {
            short8 a = *reinterpret_cast<const short8*>(&Ah[wave * 32 + mt * 16 + c][q * 8]);
            #pragma unroll
            for (int nt = 0; nt < 4; ++nt) {
                acc[mt][nt] = __builtin_amdgcn_mfma_f32_16x16x32_bf16(a, bh[nt], acc[mt][nt], 0, 0, 0);
                acc[mt][nt] = __builtin_amdgcn_mfma_f32_16x16x32_bf16(a, bl[nt], acc[mt][nt], 0, 0, 0);
            }
        }
        __syncthreads();
    }

    float asv[4], adv[4];
    #pragma unroll
    for (int nt = 0; nt < 4; ++nt) { asv[nt] = as_[nt * 16 + c]; adv[nt] = ad_[nt * 16 + c]; }
    #pragma unroll
    for (int mt = 0; mt < 2; ++mt) {
        #pragma unroll
        for (int r = 0; r < 4; ++r) {
            int gr = bm + wave * 32 + mt * 16 + q * 4 + r;
            bool ok = gr < M;
            if (ok) {
                #pragma unroll
                for (int nt = 0; nt < 4; ++nt)
                    Cb[(size_t)gr * 64 + nt * 16 + c] = f2bf(acc[mt][nt][r]);
            }
            float s = 0.f, d = 0.f;
            #pragma unroll
            for (int nt = 0; nt < 4; ++nt) {
                s += acc[mt][nt][r] * asv[nt];
                d += acc[mt][nt][r] * adv[nt];
            }
            #pragma unroll
            for (int off = 1; off < 16; off <<= 1) {
                s += __shfl_xor(s, off, 64);
                d += __shfl_xor(d, off, 64);
            }
            if (c == 0 && ok) { es[gr] = s; ed[gr] = d; }
        }
    }
}

// ---------------- fused per-dst aggregation, H=4, bf16 gather, single-pass softmax ----------------
template <int ACT, int OUTMODE>
__global__ __launch_bounds__(256) void agg4_kernel(const unsigned short* __restrict__ hb,
                                                   const float* __restrict__ es,
                                                   const float* __restrict__ ed,
                                                   const int* __restrict__ rowptr,
                                                   const int* __restrict__ col,
                                                   const float* __restrict__ bias,
                                                   void* __restrict__ outp, int N) {
    __shared__ uint2 spds[4][4][66];   // [sub][head][edge] = (src, p)
    int sub  = threadIdx.x >> 6;
    int lane = threadIdx.x & 63;
    int node = blockIdx.x * 4 + sub;
    if (node >= N) return;
    int s = rowptr[node], t = rowptr[node + 1];

    float edv[4];
    #pragma unroll
    for (int h = 0; h < 4; ++h) edv[h] = ed[(size_t)node * 4 + h];

    int hh = lane >> 4;
    float den = 0.f;
    float4 acc = make_float4(0.f, 0.f, 0.f, 0.f);
    for (int base = s; base < t; base += 64) {
        int j = base + lane;
        int m = t - base; if (m > 64) m = 64;
        int sc = 0;
        float p[4] = {0.f, 0.f, 0.f, 0.f};
        if (j < t) {
            sc = col[j];
            float4 e4 = *reinterpret_cast<const float4*>(es + (size_t)sc * 4);
            p[0] = __expf(lrelu02(e4.x + edv[0]));
            p[1] = __expf(lrelu02(e4.y + edv[1]));
            p[2] = __expf(lrelu02(e4.z + edv[2]));
            p[3] = __expf(lrelu02(e4.w + edv[3]));
        }
        #pragma unroll
        for (int h = 0; h < 4; ++h)
            spds[sub][h][lane] = make_uint2((unsigned)sc, __float_as_uint(p[h]));
        #pragma unroll 4
        for (int jj = 0; jj < m; ++jj) {
            uint2 sp = spds[sub][hh][jj];
            float a = __uint_as_float(sp.y);
            den += a;
            uint2 u = *reinterpret_cast<const uint2*>(hb + (size_t)sp.x * 256 + lane * 4);
            acc.x += bflo(u.x) * a;
            acc.y += bfhi(u.x) * a;
            acc.z += bflo(u.y) * a;
            acc.w += bfhi(u.y) * a;
        }
    }
    float inv = 1.f / den;
    float4 bv = *reinterpret_cast<const float4*>(bias + lane * 4);
    float r0 = acc.x * inv + bv.x;
    float r1 = acc.y * inv + bv.y;
    float r2 = acc.z * inv + bv.z;
    float r3 = acc.w * inv + bv.w;
    if (ACT) { r0 = eluf(r0); r1 = eluf(r1); r2 = eluf(r2); r3 = eluf(r3); }
    if constexpr (OUTMODE == 0) {
        *reinterpret_cast<float4*>((float*)outp + (size_t)node * 256 + lane * 4) =
            make_float4(r0, r1, r2, r3);
    } else {
        ushort4 o;
        o.x = f2bf(r0); o.y = f2bf(r1); o.z = f2bf(r2); o.w = f2bf(r3);
        *reinterpret_cast<ushort4*>((unsigned short*)outp + (size_t)node * 256 + lane * 4) = o;
    }
}

// ---------------- fused per-dst aggregation, H=1, bf16 gather, quarter-wave uint2 ----------------
// 16 lanes x 8 B = one 128 B row; 4 edges per wave-iter.
__global__ __launch_bounds__(256) void agg1_kernel(const unsigned short* __restrict__ hb,
                                                   const float* __restrict__ es,
                                                   const float* __restrict__ ed,
                                                   const int* __restrict__ rowptr,
                                                   const int* __restrict__ col,
                                                   const float* __restrict__ bias,
                                                   float* __restrict__ out, int N) {
    __shared__ uint2 spds[4][66];
    int sub  = threadIdx.x >> 6;
    int lane = threadIdx.x & 63;
    int node = blockIdx.x * 4 + sub;
    if (node >= N) return;
    int s = rowptr[node], t = rowptr[node + 1];
    float edv = ed[node];

    int qg = lane >> 4, ql = lane & 15;     // edge subgroup, dim quad
    float den = 0.f;
    float4 acc = make_float4(0.f, 0.f, 0.f, 0.f);   // dims ql*4 .. ql*4+3
    for (int base = s; base < t; base += 64) {
        int j = base + lane;
        int m = t - base; if (m > 64) m = 64;
        int sc = 0;
        float p0 = 0.f;
        if (j < t) {
            sc = col[j];
            p0 = __expf(lrelu02(es[sc] + edv));
        }
        spds[sub][lane] = make_uint2((unsigned)sc, __float_as_uint(p0));
        int nit = (m + 3) >> 2;
        #pragma unroll 4
        for (int it = 0; it < nit; ++it) {
            int idx = 4 * it + qg;          // phantom edges have p=0 (all 64 slots written)
            uint2 sp = spds[sub][idx];
            float a = __uint_as_float(sp.y);
            den += a;
            uint2 u = *reinterpret_cast<const uint2*>(hb + (size_t)sp.x * 64 + ql * 4);
            acc.x += bflo(u.x) * a;
            acc.y += bfhi(u.x) * a;
            acc.z += bflo(u.y) * a;
            acc.w += bfhi(u.y) * a;
        }
    }
    // combine the 4 edge subgroups
    acc.x += __shfl_xor(acc.x, 16, 64); acc.x += __shfl_xor(acc.x, 32, 64);
    acc.y += __shfl_xor(acc.y, 16, 64); acc.y += __shfl_xor(acc.y, 32, 64);
    acc.z += __shfl_xor(acc.z, 16, 64); acc.z += __shfl_xor(acc.z, 32, 64);
    acc.w += __shfl_xor(acc.w, 16, 64); acc.w += __shfl_xor(acc.w, 32, 64);
    den   += __shfl_xor(den, 16, 64);   den   += __shfl_xor(den, 32, 64);
    if (qg == 0) {
        float inv = 1.f / den;
        float4 b = *reinterpret_cast<const float4*>(bias + ql * 4);
        *reinterpret_cast<float4*>(out + (size_t)node * 64 + ql * 4) =
            make_float4(acc.x * inv + b.x, acc.y * inv + b.y,
                        acc.z * inv + b.z, acc.w * inv + b.w);
    }
}

// ---------------- graph mean ----------------
__global__ __launch_bounds__(256) void gmean_partial(const float* __restrict__ ne,
                                                     float* __restrict__ part, int N) {
    int d = threadIdx.x & 63, sub = threadIdx.x >> 6;
    int start = blockIdx.x * 4 + sub;
    float s = 0.f;
    for (int n = start; n < N; n += gridDim.x * 4) s += ne[(size_t)n * 64 + d];
    __shared__ float ls[256];
    ls[threadIdx.x] = s;
    __syncthreads();
    if (threadIdx.x < 64) {
        float v = ls[threadIdx.x] + ls[threadIdx.x + 64] + ls[threadIdx.x + 128] + ls[threadIdx.x + 192];
        part[blockIdx.x * 64 + d] = v;
    }
}

__global__ __launch_bounds__(64) void gmean_final(const float* __restrict__ part,
                                                  float* __restrict__ gout, int nblk, float invN) {
    int d = threadIdx.x;
    float s = 0.f;
    for (int b = 0; b < nblk; ++b) s += part[b * 64 + d];
    gout[d] = s * invN;
}

extern "C" void kernel_launch(void* const* d_in, const int* in_sizes, int n_in,
                              void* d_out, int out_size, void* d_ws, size_t ws_size,
                              hipStream_t stream) {
    const float* x   = (const float*)d_in[0];
    const int*   ei  = (const int*)d_in[1];
    const float* W1  = (const float*)d_in[2];
    const float* a1s = (const float*)d_in[3];
    const float* a1d = (const float*)d_in[4];
    const float* b1  = (const float*)d_in[5];
    const float* W2  = (const float*)d_in[6];
    const float* a2s = (const float*)d_in[7];
    const float* a2d = (const float*)d_in[8];
    const float* b2  = (const float*)d_in[9];
    const float* W3  = (const float*)d_in[10];
    const float* a3s = (const float*)d_in[11];
    const float* a3d = (const float*)d_in[12];
    const float* b3  = (const float*)d_in[13];
    float* out = (float*)d_out;

    const int N = NNODES;
    const int E = in_sizes[1] / 2;  // 800000
    const int NB = (N + 255) / 256;

    // workspace carve (16B alignment maintained)
    char* w = (char*)d_ws;
    unsigned short* Hb   = (unsigned short*)w; w += (size_t)N * 256 * 2;  // h2 bf16 (agg4 gather)
    unsigned short* B0b  = (unsigned short*)w; w += (size_t)N * 256 * 2;  // agg2 out bf16 (gemm3 A)
    unsigned short* H3b  = (unsigned short*)w; w += (size_t)N * 64 * 2;   // h3 bf16 (agg1 gather)
    unsigned short* A1h  = (unsigned short*)w; w += (size_t)N * 256 * 2;  // h1' bf16 (gemm2 A)
    float* zn = (float*)w; w += (size_t)N * 64 * 4;                       // layer-1 x-space agg
    float* es = (float*)w; w += (size_t)N * 4 * 4;
    float* ed = (float*)w; w += (size_t)N * 4 * 4;
    unsigned short* W2Th = (unsigned short*)w; w += 256 * 256 * 2;
    unsigned short* W2Tl = (unsigned short*)w; w += 256 * 256 * 2;
    unsigned short* W3Th = (unsigned short*)w; w += 64 * 256 * 2;
    unsigned short* W3Tl = (unsigned short*)w; w += 64 * 256 * 2;
    float* w1s = (float*)w; w += 64 * 4;
    float* w1d = (float*)w; w += 64 * 4;
    int* deg    = (int*)w; w += (size_t)N * 4;
    int* rowptr = (int*)w; w += (size_t)(N + 2) * 4;
    int* rank   = (int*)w; w += (size_t)E * 4;
    int* col    = (int*)w; w += (size_t)(E + N) * 4;
    int* bsum   = (int*)w; w += 256 * 4;
    int* boff   = (int*)w; w += 256 * 4;
    float* part = (float*)w; w += 128 * 64 * 4;
    (void)ws_size; (void)n_in; (void)out_size;

    // ---- CSR build (rank-based, atomic-free scatter) ----
    hipMemsetAsync(deg, 0, (size_t)N * 4, stream);
    deg_count_kernel<<<(E + 255) / 256, 256, 0, stream>>>(ei, deg, rank, E);
    scan_partial_kernel<<<NB, 256, 0, stream>>>(deg, bsum, N);
    scan_blocks_kernel<<<1, 256, 0, stream>>>(bsum, boff, rowptr + N, NB);
    scan_final_kernel<<<NB, 256, 0, stream>>>(deg, boff, rowptr, N);
    scatter_kernel<<<(E + N + 255) / 256, 256, 0, stream>>>(ei, rank, deg, rowptr, col, E, N);
    // weight prep (W2/W3 split + w1s/w1d vectors)
    wprep_kernel<<<321, 256, 0, stream>>>(W1, a1s, a1d, W2, W3,
                                          W2Th, W2Tl, W3Th, W3Tl, w1s, w1d);

    // ---- Layer 1 (x-space aggregation): es1/ed1 -> aggx -> gemm1z ----
    esed1_kernel<<<NB, 256, 0, stream>>>(x, w1s, w1d, es, ed, N);
    aggx_kernel<<<(N + 3) / 4, 256, 0, stream>>>(x, es, ed, rowptr, col, zn, N);
    gemm1z_kernel<<<dim3((N + 63) / 64, 4), 256, 0, stream>>>(zn, W1, b1, A1h, N);

    // ---- Layer 2: A1h[N,256] @ W2 (bf16-A, split-W MFMA); then agg4 on h2 ----
    gemm2_mfma_kernel<<<dim3((N + 127) / 128, 2), 256, 0, stream>>>(
        A1h, W2Th, W2Tl, Hb, a2s, a2d, es, ed, N);
    agg4_kernel<1, 1><<<(N + 3) / 4, 256, 0, stream>>>(Hb, es, ed, rowptr, col, b2, B0b, N);

    // ---- Layer 3: B0b[N,256] @ W3, bf16-A MFMA; agg1 on h3 ----
    gemm3_mfma_kernel<<<(N + 127) / 128, 256, 0, stream>>>(
        B0b, W3Th, W3Tl, H3b, a3s, a3d, es, ed, N);
    agg1_kernel<<<(N + 3) / 4, 256, 0, stream>>>(H3b, es, ed, rowptr, col, b3, out, N);

    // ---- graph mean ----
    gmean_partial<<<128, 256, 0, stream>>>(out, part, N);
    gmean_final<<<1, 64, 0, stream>>>(part, out + (size_t)N * 64, 128, 1.0f / N);
}